// Round 3
// baseline (2119.558 us; speedup 1.0000x reference)
//
#include <hip/hip_runtime.h>
#include <math.h>

#define Bsz 8192
#define Hd  512
#define Vd  512
#define Ld  16
#define G4  2048   // 4*Hd

using short8 = __attribute__((ext_vector_type(8))) short;
using f32x4  = __attribute__((ext_vector_type(4))) float;

// fast device math: v_exp_f32 / v_rcp_f32 (~1 ulp; far below split-GEMM noise)
__device__ __forceinline__ float sigm_f(float x){
  return __builtin_amdgcn_rcpf(1.0f + __expf(-x));
}
__device__ __forceinline__ float tanh_f(float x){
  return 1.0f - 2.0f * __builtin_amdgcn_rcpf(1.0f + __expf(2.0f * x));
}

// bf16 bit helpers (RNE)
__device__ __forceinline__ unsigned short f2bf(float f){
  unsigned int u = __float_as_uint(f);
  u = (u + 0x7fffu + ((u >> 16) & 1u)) >> 16;
  return (unsigned short)u;
}
__device__ __forceinline__ float bf2f(unsigned short b){
  return __uint_as_float(((unsigned int)b) << 16);
}

__device__ __forceinline__ void gl_lds16(const void* g, void* l){
  __builtin_amdgcn_global_load_lds((const __attribute__((address_space(1))) void*)g,
                                   (__attribute__((address_space(3))) void*)l, 16, 0, 0);
}

// ---------------------------------------------------------------------------
// Transpose W_ih (2048 x 512) -> W_ihT (512 x 2048): one-hot gather rows.
// ---------------------------------------------------------------------------
__global__ __launch_bounds__(256) void k_transpose(const float* __restrict__ in,
                                                   float* __restrict__ out){
  __shared__ float tile[32][33];
  const int tx = threadIdx.x, ty = threadIdx.y;
  const int v0 = blockIdx.x * 32, n0 = blockIdx.y * 32;
#pragma unroll
  for(int i=0;i<4;i++)
    tile[ty+i*8][tx] = in[(size_t)(n0+ty+i*8)*Vd + v0+tx];
  __syncthreads();
#pragma unroll
  for(int i=0;i<4;i++)
    out[(size_t)(v0+ty+i*8)*G4 + n0+tx] = tile[tx][ty+i*8];
}

// ---------------------------------------------------------------------------
// Split fp32 -> (bf16 hi, bf16 lo)
// ---------------------------------------------------------------------------
__global__ __launch_bounds__(256) void k_split(const float* __restrict__ src,
                                               unsigned short* __restrict__ hi,
                                               unsigned short* __restrict__ lo, int n){
  const int i = blockIdx.x*256 + threadIdx.x;
  if(i < n){
    const float x = src[i];
    const unsigned short h = f2bf(x);
    hi[i] = h;
    lo[i] = f2bf(x - bf2f(h));
  }
}

// ---------------------------------------------------------------------------
// Kernel A: fused LSTM step via MFMA (bf16x2, 3 products).
// Block tile: 128 batch x (32 j x 4 gates).  Wave: 64 batch x 16 j x 4 gates.
// ---------------------------------------------------------------------------
__global__ __launch_bounds__(256) void k_lstm_mfma(
    const unsigned short* __restrict__ hh, const unsigned short* __restrict__ hl,
    const float* __restrict__ cin,
    unsigned short* __restrict__ hout_hi, unsigned short* __restrict__ hout_lo,
    float* __restrict__ cout,
    const unsigned short* __restrict__ Whh_hi, const unsigned short* __restrict__ Whh_lo,
    const float* __restrict__ WihT, const float* __restrict__ bih,
    const float* __restrict__ bhh, const int* __restrict__ xidx, int step)
{
  __shared__ unsigned short lds[16384];        // 32 KB
  unsigned short* Ahi = lds;                   // 128x32
  unsigned short* Alo = lds + 4096;
  unsigned short* Bhi = lds + 8192;
  unsigned short* Blo = lds + 12288;

  const int tid = threadIdx.x;
  const int wave = tid >> 6, lane = tid & 63;
  const int mb = blockIdx.x * 128;
  const int jb = blockIdx.y * 32;
  const int m_wave = (wave & 1) * 64;
  const int j_wave = (wave >> 1) * 16;

  f32x4 acc[4][4];
#pragma unroll
  for(int g=0;g<4;g++)
#pragma unroll
    for(int mt=0;mt<4;mt++) acc[g][mt] = (f32x4){0.f,0.f,0.f,0.f};

  const int lr = lane >> 2;
  const int jj = lane & 3;
  const int fr = lane & 15, q = lane >> 4;

  for(int k0=0; k0<Hd; k0+=32){
#pragma unroll
    for(int p=0;p<2;p++){
      const int s = wave*2 + p;
      const int r = s*16 + lr;
      const int j = jj ^ ((r >> 1) & 3);
      const size_t ka = (size_t)k0 + j*8;
      gl_lds16(hh + (size_t)(mb + r)*Hd + ka, &Ahi[s*512]);
      gl_lds16(hl + (size_t)(mb + r)*Hd + ka, &Alo[s*512]);
      const size_t brow = (size_t)((r >> 5)*Hd + jb + (r & 31));
      gl_lds16(Whh_hi + brow*Hd + ka, &Bhi[s*512]);
      gl_lds16(Whh_lo + brow*Hd + ka, &Blo[s*512]);
    }
    __syncthreads();

    short8 ah[4], al[4], bh[4], bl[4];
#pragma unroll
    for(int mt=0;mt<4;mt++){
      const int r = m_wave + mt*16 + fr;
      const int off = r*32 + ((q ^ ((r >> 1) & 3)) << 3);
      ah[mt] = *(const short8*)&Ahi[off];
      al[mt] = *(const short8*)&Alo[off];
    }
#pragma unroll
    for(int g=0;g<4;g++){
      const int r = g*32 + j_wave + fr;
      const int off = r*32 + ((q ^ ((r >> 1) & 3)) << 3);
      bh[g] = *(const short8*)&Bhi[off];
      bl[g] = *(const short8*)&Blo[off];
    }
#pragma unroll
    for(int g=0;g<4;g++)
#pragma unroll
      for(int mt=0;mt<4;mt++){
        acc[g][mt] = __builtin_amdgcn_mfma_f32_16x16x32_bf16(ah[mt], bh[g], acc[g][mt], 0,0,0);
        acc[g][mt] = __builtin_amdgcn_mfma_f32_16x16x32_bf16(ah[mt], bl[g], acc[g][mt], 0,0,0);
        acc[g][mt] = __builtin_amdgcn_mfma_f32_16x16x32_bf16(al[mt], bh[g], acc[g][mt], 0,0,0);
      }
    __syncthreads();
  }

  const int j = jb + j_wave + fr;
  float bsum[4];
#pragma unroll
  for(int g=0;g<4;g++) bsum[g] = bih[g*Hd + j] + bhh[g*Hd + j];
  const int rb = (lane >> 4) * 4;
#pragma unroll
  for(int mt=0;mt<4;mt++){
#pragma unroll
    for(int reg=0;reg<4;reg++){
      const int b = mb + m_wave + mt*16 + rb + reg;
      float g0 = acc[0][mt][reg] + bsum[0];
      float g1 = acc[1][mt][reg] + bsum[1];
      float g2 = acc[2][mt][reg] + bsum[2];
      float g3 = acc[3][mt][reg] + bsum[3];
      if(step > 0){
        const float* grow = WihT + (size_t)xidx[b]*G4 + j;
        g0 += grow[0]; g1 += grow[Hd]; g2 += grow[2*Hd]; g3 += grow[3*Hd];
      }
      const size_t idx = (size_t)b*Hd + j;
      const float co = cin[idx];
      const float I = sigm_f(g0), F = sigm_f(g1), G = tanh_f(g2), O = sigm_f(g3);
      const float cn = F*co + I*G;
      const float hn = O*tanh_f(cn);
      cout[idx] = cn;
      const unsigned short hb = f2bf(hn);
      hout_hi[idx] = hb;
      hout_lo[idx] = f2bf(hn - bf2f(hb));
    }
  }
}

// ---------------------------------------------------------------------------
// Kernel BC (fused): logits GEMM (bf16x2, 3 products) + online softmax/argmax
// + one-hot message + masks/lp/xidx.  NO logits materialization.
// Block: 32 batch rows x full V=512.  Wave w owns cols [w*128, w*128+128).
// ---------------------------------------------------------------------------
__global__ __launch_bounds__(256, 2) void k_out(
    const unsigned short* __restrict__ hh, const unsigned short* __restrict__ hl,
    const unsigned short* __restrict__ Wh, const unsigned short* __restrict__ Wl,
    const float* __restrict__ bout,
    float* __restrict__ msg, float* __restrict__ masks_out,
    float* __restrict__ lp_out, float* __restrict__ lpbuf,
    float* __restrict__ mbuf, int* __restrict__ xidx, int step)
{
  __shared__ unsigned short Ahi[1024], Alo[1024];     // 32 x 32
  __shared__ unsigned short Bhi[16384], Blo[16384];   // 512 x 32
  __shared__ float redM[4][32];
  __shared__ float redS[4][32];
  __shared__ int   redI[4][32];
  __shared__ int   gI[32];

  const int tid = threadIdx.x;
  const int wave = tid >> 6, lane = tid & 63;
  const int mb = blockIdx.x * 32;
  const int vb = wave * 128;

  f32x4 acc[2][8];
#pragma unroll
  for(int mt=0;mt<2;mt++)
#pragma unroll
    for(int nt=0;nt<8;nt++) acc[mt][nt] = (f32x4){0.f,0.f,0.f,0.f};

  const int lr = lane >> 2, jj = lane & 3;
  const int fr = lane & 15, q = lane >> 4;

  for(int k0=0; k0<Hd; k0+=32){
    // A tile (32 rows): wave0 stages hi, wave1 stages lo
    if(wave == 0){
#pragma unroll
      for(int p=0;p<2;p++){
        const int r = p*16 + lr;
        const int j = jj ^ ((r >> 1) & 3);
        gl_lds16(hh + (size_t)(mb + r)*Hd + k0 + j*8, &Ahi[p*512]);
      }
    } else if(wave == 1){
#pragma unroll
      for(int p=0;p<2;p++){
        const int r = p*16 + lr;
        const int j = jj ^ ((r >> 1) & 3);
        gl_lds16(hl + (size_t)(mb + r)*Hd + k0 + j*8, &Alo[p*512]);
      }
    }
    // B tile: each wave stages its own 128 rows (cols of W_out)
#pragma unroll
    for(int p=0;p<8;p++){
      const int r = vb + p*16 + lr;
      const int j = jj ^ ((r >> 1) & 3);
      const size_t ka = (size_t)k0 + j*8;
      gl_lds16(Wh + (size_t)r*Hd + ka, &Bhi[(vb + p*16)*32]);
      gl_lds16(Wl + (size_t)r*Hd + ka, &Blo[(vb + p*16)*32]);
    }
    __syncthreads();

    short8 ah[2], al[2], bh[8], bl[8];
#pragma unroll
    for(int mt=0;mt<2;mt++){
      const int r = mt*16 + fr;
      const int off = r*32 + ((q ^ ((r >> 1) & 3)) << 3);
      ah[mt] = *(const short8*)&Ahi[off];
      al[mt] = *(const short8*)&Alo[off];
    }
#pragma unroll
    for(int nt=0;nt<8;nt++){
      const int r = vb + nt*16 + fr;
      const int off = r*32 + ((q ^ ((r >> 1) & 3)) << 3);
      bh[nt] = *(const short8*)&Bhi[off];
      bl[nt] = *(const short8*)&Blo[off];
    }
#pragma unroll
    for(int nt=0;nt<8;nt++)
#pragma unroll
      for(int mt=0;mt<2;mt++){
        acc[mt][nt] = __builtin_amdgcn_mfma_f32_16x16x32_bf16(ah[mt], bh[nt], acc[mt][nt], 0,0,0);
        acc[mt][nt] = __builtin_amdgcn_mfma_f32_16x16x32_bf16(ah[mt], bl[nt], acc[mt][nt], 0,0,0);
        acc[mt][nt] = __builtin_amdgcn_mfma_f32_16x16x32_bf16(al[mt], bh[nt], acc[mt][nt], 0,0,0);
      }
    __syncthreads();
  }

  // per-row online-softmax stats for this wave's 128-col slab
  float bo[8];
#pragma unroll
  for(int nt=0;nt<8;nt++) bo[nt] = bout[vb + nt*16 + fr];

#pragma unroll
  for(int mt=0;mt<2;mt++){
#pragma unroll
    for(int reg=0;reg<4;reg++){
      const int r32 = mt*16 + q*4 + reg;        // row within block
      float vmax = acc[mt][0][reg] + bo[0];
      int   imax = vb + fr;
#pragma unroll
      for(int nt=1;nt<8;nt++){
        const float v = acc[mt][nt][reg] + bo[nt];
        if(v > vmax){ vmax = v; imax = vb + nt*16 + fr; }
      }
#pragma unroll
      for(int off=1; off<16; off<<=1){
        const float vo = __shfl_xor(vmax, off);
        const int   io = __shfl_xor(imax, off);
        if(vo > vmax || (vo == vmax && io < imax)){ vmax = vo; imax = io; }
      }
      float s = 0.0f;
#pragma unroll
      for(int nt=0;nt<8;nt++) s += __expf(acc[mt][nt][reg] + bo[nt] - vmax);
#pragma unroll
      for(int off=1; off<16; off<<=1) s += __shfl_xor(s, off);
      if(fr == 0){
        redM[wave][r32] = vmax;
        redI[wave][r32] = imax;
        redS[wave][r32] = s;
      }
    }
  }
  __syncthreads();

  // merge the 4 wave-slabs; write scalars
  if(tid < 32){
    float gm = redM[0][tid]; int gi = redI[0][tid];
#pragma unroll
    for(int w=1;w<4;w++){
      const float m = redM[w][tid];
      if(m > gm){ gm = m; gi = redI[w][tid]; }   // ties: earlier wave = smaller col
    }
    float tot = 0.0f;
#pragma unroll
    for(int w=0;w<4;w++) tot += redS[w][tid] * __expf(redM[w][tid] - gm);
    const int row = mb + tid;
    const float logp = -__logf(tot);
    const float mo  = (step == 0) ? 1.0f : mbuf[row];
    const float lpo = (step == 0) ? 0.0f : lpbuf[row];
    const float lpn = lpo + logp * mo;
    masks_out[(size_t)step * Bsz + row] = mo;
    lp_out[row] = lpn;
    lpbuf[row]  = lpn;
    mbuf[row]   = mo * ((gi == Vd-1) ? 0.0f : 1.0f);
    xidx[row]   = gi;
    gI[tid] = gi;
  }
  __syncthreads();

  // one-hot message write: 32 rows x 512 cols; 256 threads x 16 float4
  const int r  = tid >> 3;
  const int c8 = tid & 7;
  const int gi = gI[r];
  float* mrow = msg + ((size_t)step * Bsz + mb + r) * Vd;
#pragma unroll
  for(int i=0;i<16;i++){
    const int c = (i*8 + c8) * 4;
    float4 v;
    v.x = (c   == gi) ? 1.0f : 0.0f;
    v.y = (c+1 == gi) ? 1.0f : 0.0f;
    v.z = (c+2 == gi) ? 1.0f : 0.0f;
    v.w = (c+3 == gi) ? 1.0f : 0.0f;
    *(float4*)&mrow[c] = v;
  }
}

// ---------------------------------------------------------------------------
extern "C" void kernel_launch(void* const* d_in, const int* in_sizes, int n_in,
                              void* d_out, int out_size, void* d_ws, size_t ws_size,
                              hipStream_t stream) {
  const float* enc_h = (const float*)d_in[0];
  const float* enc_c = (const float*)d_in[1];
  const float* Wih   = (const float*)d_in[2];
  const float* Whh   = (const float*)d_in[3];
  const float* bih   = (const float*)d_in[4];
  const float* bhh   = (const float*)d_in[5];
  const float* Wout  = (const float*)d_in[6];
  const float* bout  = (const float*)d_in[7];

  float* out_msg   = (float*)d_out;                       // [16][8192][512]
  float* out_masks = out_msg + (size_t)Ld * Bsz * Vd;     // [16][1][8192]
  float* out_lp    = out_masks + (size_t)Ld * Bsz;        // [8192]

  char* ws = (char*)d_ws;
  float* WihT  = (float*)ws;          ws += (size_t)Vd * G4 * 4;
  unsigned short* WhhHi = (unsigned short*)ws; ws += (size_t)G4 * Hd * 2;
  unsigned short* WhhLo = (unsigned short*)ws; ws += (size_t)G4 * Hd * 2;
  unsigned short* WoHi  = (unsigned short*)ws; ws += (size_t)Vd * Hd * 2;
  unsigned short* WoLo  = (unsigned short*)ws; ws += (size_t)Vd * Hd * 2;
  unsigned short* hhi0  = (unsigned short*)ws; ws += (size_t)Bsz * Hd * 2;
  unsigned short* hlo0  = (unsigned short*)ws; ws += (size_t)Bsz * Hd * 2;
  unsigned short* hhi1  = (unsigned short*)ws; ws += (size_t)Bsz * Hd * 2;
  unsigned short* hlo1  = (unsigned short*)ws; ws += (size_t)Bsz * Hd * 2;
  float* cbuf   = (float*)ws;  ws += (size_t)Bsz * Hd * 4;
  float* lpbuf  = (float*)ws;  ws += (size_t)Bsz * 4;
  float* mbuf   = (float*)ws;  ws += (size_t)Bsz * 4;
  int*   xidx   = (int*)ws;    ws += (size_t)Bsz * 4;

  k_transpose<<<dim3(Vd/32, G4/32), dim3(32,8), 0, stream>>>(Wih, WihT);
  k_split<<<(G4*Hd+255)/256, 256, 0, stream>>>(Whh,  WhhHi, WhhLo, G4*Hd);
  k_split<<<(Vd*Hd+255)/256, 256, 0, stream>>>(Wout, WoHi,  WoLo,  Vd*Hd);
  k_split<<<(Bsz*Hd+255)/256, 256, 0, stream>>>(enc_h, hhi0, hlo0, Bsz*Hd);

  for(int t=0; t<Ld; t++){
    const unsigned short* hih = (t & 1) ? hhi1 : hhi0;
    const unsigned short* hil = (t & 1) ? hlo1 : hlo0;
    unsigned short* hoh = (t & 1) ? hhi0 : hhi1;
    unsigned short* hol = (t & 1) ? hlo0 : hlo1;
    const float* ci = (t == 0) ? enc_c : cbuf;

    k_lstm_mfma<<<dim3(Bsz/128, Hd/32), 256, 0, stream>>>(
        hih, hil, ci, hoh, hol, cbuf, WhhHi, WhhLo, WihT, bih, bhh, xidx, t);
    k_out<<<Bsz/32, 256, 0, stream>>>(hoh, hol, WoHi, WoLo, bout,
                                      out_msg, out_masks, out_lp,
                                      lpbuf, mbuf, xidx, t);
  }
}

// Round 4
// 1809.600 us; speedup vs baseline: 1.1713x; 1.1713x over previous
//
#include <hip/hip_runtime.h>
#include <math.h>

#define Bsz 8192
#define Hd  512
#define Vd  512
#define Ld  16
#define G4  2048   // 4*Hd

using short8 = __attribute__((ext_vector_type(8))) short;
using f32x4  = __attribute__((ext_vector_type(4))) float;

__device__ __forceinline__ float sigm_f(float x){
  return __builtin_amdgcn_rcpf(1.0f + __expf(-x));
}
__device__ __forceinline__ float tanh_f(float x){
  return 1.0f - 2.0f * __builtin_amdgcn_rcpf(1.0f + __expf(2.0f * x));
}

// bf16 bit helpers (RNE)
__device__ __forceinline__ unsigned short f2bf(float f){
  unsigned int u = __float_as_uint(f);
  u = (u + 0x7fffu + ((u >> 16) & 1u)) >> 16;
  return (unsigned short)u;
}
__device__ __forceinline__ float bf2f(unsigned short b){
  return __uint_as_float(((unsigned int)b) << 16);
}

__device__ __forceinline__ void gl_lds16(const void* g, void* l){
  __builtin_amdgcn_global_load_lds((const __attribute__((address_space(1))) void*)g,
                                   (__attribute__((address_space(3))) void*)l, 16, 0, 0);
}

// ---------------------------------------------------------------------------
// Transpose W_ih (2048 x 512) -> W_ihT (512 x 2048): one-hot gather rows.
// ---------------------------------------------------------------------------
__global__ __launch_bounds__(256) void k_transpose(const float* __restrict__ in,
                                                   float* __restrict__ out){
  __shared__ float tile[32][33];
  const int tx = threadIdx.x, ty = threadIdx.y;
  const int v0 = blockIdx.x * 32, n0 = blockIdx.y * 32;
#pragma unroll
  for(int i=0;i<4;i++)
    tile[ty+i*8][tx] = in[(size_t)(n0+ty+i*8)*Vd + v0+tx];
  __syncthreads();
#pragma unroll
  for(int i=0;i<4;i++)
    out[(size_t)(v0+ty+i*8)*G4 + n0+tx] = tile[tx][ty+i*8];
}

// ---------------------------------------------------------------------------
// Split fp32 -> (bf16 hi, bf16 lo)
// ---------------------------------------------------------------------------
__global__ __launch_bounds__(256) void k_split(const float* __restrict__ src,
                                               unsigned short* __restrict__ hi,
                                               unsigned short* __restrict__ lo, int n){
  const int i = blockIdx.x*256 + threadIdx.x;
  if(i < n){
    const float x = src[i];
    const unsigned short h = f2bf(x);
    hi[i] = h;
    lo[i] = f2bf(x - bf2f(h));
  }
}

// ---------------------------------------------------------------------------
// Kernel A: fused LSTM step via MFMA (bf16x2, 3 products), SWAPPED operands:
// A-operand = Whh rows (gate-gathered)  -> D rows = j (4 contiguous/thread)
// B-operand = h rows                    -> D cols = batch
// Epilogue fully vectorized: float4 c, short4 h hi/lo, float4 gather.
// ---------------------------------------------------------------------------
__global__ __launch_bounds__(256) void k_lstm_mfma(
    const unsigned short* __restrict__ hh, const unsigned short* __restrict__ hl,
    const float* __restrict__ cin,
    unsigned short* __restrict__ hout_hi, unsigned short* __restrict__ hout_lo,
    float* __restrict__ cout,
    const unsigned short* __restrict__ Whh_hi, const unsigned short* __restrict__ Whh_lo,
    const float* __restrict__ WihT, const float* __restrict__ bih,
    const float* __restrict__ bhh, const int* __restrict__ xidx, int step)
{
  __shared__ unsigned short lds[16384];        // 32 KB
  unsigned short* Whi = lds;                   // 128x32 gate-gathered W rows
  unsigned short* Wlo = lds + 4096;
  unsigned short* Hhi = lds + 8192;            // 128x32 batch rows
  unsigned short* Hlo = lds + 12288;

  const int tid = threadIdx.x;
  const int wave = tid >> 6, lane = tid & 63;
  const int mb = blockIdx.x * 128;             // batch tile
  const int jb = blockIdx.y * 32;              // hidden-j tile
  const int b_wave = (wave & 1) * 64;
  const int j_wave = (wave >> 1) * 16;
  const int fr = lane & 15, q = lane >> 4;
  const int lr = lane >> 2, jj = lane & 3;

  // ---- prefetch (independent of GEMM): xidx + bias sums
  int xid[4];
  if(step > 0){
#pragma unroll
    for(int bt=0;bt<4;bt++)
      xid[bt] = xidx[mb + b_wave + bt*16 + fr];
  }
  const int j0 = jb + j_wave + q*4;            // 4 contiguous j per thread
  float bsum[4][4];
#pragma unroll
  for(int g=0;g<4;g++){
    float4 a = *(const float4*)&bih[g*Hd + j0];
    float4 b = *(const float4*)&bhh[g*Hd + j0];
    bsum[g][0]=a.x+b.x; bsum[g][1]=a.y+b.y; bsum[g][2]=a.z+b.z; bsum[g][3]=a.w+b.w;
  }

  f32x4 acc[4][4];                             // [gate][bt]
#pragma unroll
  for(int g=0;g<4;g++)
#pragma unroll
    for(int bt=0;bt<4;bt++) acc[g][bt] = (f32x4){0.f,0.f,0.f,0.f};

  for(int k0=0; k0<Hd; k0+=32){
#pragma unroll
    for(int p=0;p<2;p++){
      const int s = wave*2 + p;
      const int r = s*16 + lr;                 // tile row 0..127
      const int j = jj ^ ((r >> 1) & 3);
      const size_t ka = (size_t)k0 + j*8;
      const size_t wrow = (size_t)((r >> 5)*Hd + jb + (r & 31));
      gl_lds16(Whh_hi + wrow*Hd + ka, &Whi[s*512]);
      gl_lds16(Whh_lo + wrow*Hd + ka, &Wlo[s*512]);
      gl_lds16(hh + (size_t)(mb + r)*Hd + ka, &Hhi[s*512]);
      gl_lds16(hl + (size_t)(mb + r)*Hd + ka, &Hlo[s*512]);
    }
    __syncthreads();

    short8 wh[4], wl[4], hf[4], lf[4];
#pragma unroll
    for(int g=0;g<4;g++){
      const int r = g*32 + j_wave + fr;
      const int off = r*32 + ((q ^ ((r >> 1) & 3)) << 3);
      wh[g] = *(const short8*)&Whi[off];
      wl[g] = *(const short8*)&Wlo[off];
    }
#pragma unroll
    for(int bt=0;bt<4;bt++){
      const int r = b_wave + bt*16 + fr;
      const int off = r*32 + ((q ^ ((r >> 1) & 3)) << 3);
      hf[bt] = *(const short8*)&Hhi[off];
      lf[bt] = *(const short8*)&Hlo[off];
    }
#pragma unroll
    for(int g=0;g<4;g++)
#pragma unroll
      for(int bt=0;bt<4;bt++){
        acc[g][bt] = __builtin_amdgcn_mfma_f32_16x16x32_bf16(wh[g], hf[bt], acc[g][bt], 0,0,0);
        acc[g][bt] = __builtin_amdgcn_mfma_f32_16x16x32_bf16(wh[g], lf[bt], acc[g][bt], 0,0,0);
        acc[g][bt] = __builtin_amdgcn_mfma_f32_16x16x32_bf16(wl[g], hf[bt], acc[g][bt], 0,0,0);
      }
    __syncthreads();
  }

  // ---- epilogue: 4 batch positions x 4 contiguous j, all vectorized
#pragma unroll
  for(int bt=0;bt<4;bt++){
    const int b = mb + b_wave + bt*16 + fr;
    const size_t idx = (size_t)b*Hd + j0;
    float gv[4][4];
#pragma unroll
    for(int g=0;g<4;g++)
#pragma unroll
      for(int r=0;r<4;r++) gv[g][r] = acc[g][bt][r] + bsum[g][r];
    if(step > 0){
      const float* grow = WihT + (size_t)xid[bt]*G4 + j0;
#pragma unroll
      for(int g=0;g<4;g++){
        float4 x = *(const float4*)&grow[g*Hd];
        gv[g][0]+=x.x; gv[g][1]+=x.y; gv[g][2]+=x.z; gv[g][3]+=x.w;
      }
    }
    float co[4];
    *(float4*)co = *(const float4*)&cin[idx];
    float cn[4];
    unsigned short hi4[4], lo4[4];
#pragma unroll
    for(int r=0;r<4;r++){
      const float I = sigm_f(gv[0][r]);
      const float F = sigm_f(gv[1][r]);
      const float G = tanh_f(gv[2][r]);
      const float O = sigm_f(gv[3][r]);
      cn[r] = F*co[r] + I*G;
      const float hn = O*tanh_f(cn[r]);
      const unsigned short hb = f2bf(hn);
      hi4[r] = hb;
      lo4[r] = f2bf(hn - bf2f(hb));
    }
    *(float4*)&cout[idx] = *(float4*)cn;
    *(short4*)&hout_hi[idx] = *(short4*)hi4;
    *(short4*)&hout_lo[idx] = *(short4*)lo4;
  }
}

// ---------------------------------------------------------------------------
// Kernel B: logits stats (bf16x2, 3 products). 128x128 tile as round-2
// k_logits, but NO logits write: per-row (max, argmax, sumexp) over each
// 64-col slab -> stat buffers [8][B].
// ---------------------------------------------------------------------------
__global__ __launch_bounds__(256) void k_logits_stats(
    const unsigned short* __restrict__ hh, const unsigned short* __restrict__ hl,
    const unsigned short* __restrict__ Wh, const unsigned short* __restrict__ Wl,
    const float* __restrict__ bout,
    float* __restrict__ statM, float* __restrict__ statS, int* __restrict__ statI)
{
  __shared__ unsigned short lds[16384];
  unsigned short* Ahi = lds;
  unsigned short* Alo = lds + 4096;
  unsigned short* Bhi = lds + 8192;
  unsigned short* Blo = lds + 12288;

  const int tid = threadIdx.x;
  const int wave = tid >> 6, lane = tid & 63;
  const int mb = blockIdx.x * 128;
  const int vb = blockIdx.y * 128;
  const int m_wave = (wave & 1) * 64;
  const int n_wave = (wave >> 1) * 64;
  const int fr = lane & 15, q = lane >> 4;
  const int lr = lane >> 2, jj = lane & 3;

  f32x4 acc[4][4];                             // [nt][mt]
#pragma unroll
  for(int nt=0;nt<4;nt++)
#pragma unroll
    for(int mt=0;mt<4;mt++) acc[nt][mt] = (f32x4){0.f,0.f,0.f,0.f};

  for(int k0=0; k0<Hd; k0+=32){
#pragma unroll
    for(int p=0;p<2;p++){
      const int s = wave*2 + p;
      const int r = s*16 + lr;
      const int j = jj ^ ((r >> 1) & 3);
      const size_t ka = (size_t)k0 + j*8;
      gl_lds16(hh + (size_t)(mb + r)*Hd + ka, &Ahi[s*512]);
      gl_lds16(hl + (size_t)(mb + r)*Hd + ka, &Alo[s*512]);
      gl_lds16(Wh + (size_t)(vb + r)*Hd + ka, &Bhi[s*512]);
      gl_lds16(Wl + (size_t)(vb + r)*Hd + ka, &Blo[s*512]);
    }
    __syncthreads();

    short8 ah[4], al[4], bh[4], bl[4];
#pragma unroll
    for(int mt=0;mt<4;mt++){
      const int r = m_wave + mt*16 + fr;
      const int off = r*32 + ((q ^ ((r >> 1) & 3)) << 3);
      ah[mt] = *(const short8*)&Ahi[off];
      al[mt] = *(const short8*)&Alo[off];
    }
#pragma unroll
    for(int nt=0;nt<4;nt++){
      const int r = n_wave + nt*16 + fr;
      const int off = r*32 + ((q ^ ((r >> 1) & 3)) << 3);
      bh[nt] = *(const short8*)&Bhi[off];
      bl[nt] = *(const short8*)&Blo[off];
    }
#pragma unroll
    for(int nt=0;nt<4;nt++)
#pragma unroll
      for(int mt=0;mt<4;mt++){
        acc[nt][mt] = __builtin_amdgcn_mfma_f32_16x16x32_bf16(ah[mt], bh[nt], acc[nt][mt], 0,0,0);
        acc[nt][mt] = __builtin_amdgcn_mfma_f32_16x16x32_bf16(ah[mt], bl[nt], acc[nt][mt], 0,0,0);
        acc[nt][mt] = __builtin_amdgcn_mfma_f32_16x16x32_bf16(al[mt], bh[nt], acc[nt][mt], 0,0,0);
      }
    __syncthreads();
  }

  // per-row slab stats (slab = 64 cols owned by this wave's n-range)
  const int slab = blockIdx.y*2 + (wave >> 1);
  float bo[4];
  int vv[4];
#pragma unroll
  for(int nt=0;nt<4;nt++){
    vv[nt] = vb + n_wave + nt*16 + fr;
    bo[nt] = bout[vv[nt]];
  }
#pragma unroll
  for(int mt=0;mt<4;mt++){
#pragma unroll
    for(int reg=0;reg<4;reg++){
      float vmax = acc[0][mt][reg] + bo[0];
      int   imax = vv[0];
#pragma unroll
      for(int nt=1;nt<4;nt++){
        const float v = acc[nt][mt][reg] + bo[nt];
        if(v > vmax || (v == vmax && vv[nt] < imax)){ vmax = v; imax = vv[nt]; }
      }
#pragma unroll
      for(int off=1; off<16; off<<=1){
        const float vo = __shfl_xor(vmax, off);
        const int   io = __shfl_xor(imax, off);
        if(vo > vmax || (vo == vmax && io < imax)){ vmax = vo; imax = io; }
      }
      float s = 0.0f;
#pragma unroll
      for(int nt=0;nt<4;nt++) s += __expf(acc[nt][mt][reg] + bo[nt] - vmax);
#pragma unroll
      for(int off=1; off<16; off<<=1) s += __shfl_xor(s, off);
      if(fr == 0){
        const int m = mb + m_wave + mt*16 + q*4 + reg;
        statM[(size_t)slab*Bsz + m] = vmax;
        statS[(size_t)slab*Bsz + m] = s;
        statI[(size_t)slab*Bsz + m] = imax;
      }
    }
  }
}

// ---------------------------------------------------------------------------
// Kernel C: merge 8 slabs per row; write masks/lp/xidx + one-hot message.
// Block: 32 rows.
// ---------------------------------------------------------------------------
__global__ __launch_bounds__(256) void k_merge(
    const float* __restrict__ statM, const float* __restrict__ statS,
    const int* __restrict__ statI,
    float* __restrict__ msg, float* __restrict__ masks_out,
    float* __restrict__ lp_out, float* __restrict__ lpbuf,
    float* __restrict__ mbuf, int* __restrict__ xidx, int step)
{
  __shared__ int gI[32];
  const int tid = threadIdx.x;
  const int mb = blockIdx.x * 32;

  if(tid < 32){
    const int row = mb + tid;
    float gm = statM[row]; int gi = statI[row];
#pragma unroll
    for(int s=1;s<8;s++){
      const float m = statM[(size_t)s*Bsz + row];
      if(m > gm){ gm = m; gi = statI[(size_t)s*Bsz + row]; }
    }
    float tot = 0.0f;
#pragma unroll
    for(int s=0;s<8;s++)
      tot += statS[(size_t)s*Bsz + row] * __expf(statM[(size_t)s*Bsz + row] - gm);
    const float logp = -__logf(tot);
    const float mo  = (step == 0) ? 1.0f : mbuf[row];
    const float lpo = (step == 0) ? 0.0f : lpbuf[row];
    const float lpn = lpo + logp * mo;
    masks_out[(size_t)step * Bsz + row] = mo;
    lp_out[row] = lpn;
    lpbuf[row]  = lpn;
    mbuf[row]   = mo * ((gi == Vd-1) ? 0.0f : 1.0f);
    xidx[row]   = gi;
    gI[tid] = gi;
  }
  __syncthreads();

  const int r  = tid >> 3;
  const int c8 = tid & 7;
  const int gi = gI[r];
  float* mrow = msg + ((size_t)step * Bsz + mb + r) * Vd;
#pragma unroll
  for(int i=0;i<16;i++){
    const int c = (i*8 + c8) * 4;
    float4 v;
    v.x = (c   == gi) ? 1.0f : 0.0f;
    v.y = (c+1 == gi) ? 1.0f : 0.0f;
    v.z = (c+2 == gi) ? 1.0f : 0.0f;
    v.w = (c+3 == gi) ? 1.0f : 0.0f;
    *(float4*)&mrow[c] = v;
  }
}

// ---------------------------------------------------------------------------
extern "C" void kernel_launch(void* const* d_in, const int* in_sizes, int n_in,
                              void* d_out, int out_size, void* d_ws, size_t ws_size,
                              hipStream_t stream) {
  const float* enc_h = (const float*)d_in[0];
  const float* enc_c = (const float*)d_in[1];
  const float* Wih   = (const float*)d_in[2];
  const float* Whh   = (const float*)d_in[3];
  const float* bih   = (const float*)d_in[4];
  const float* bhh   = (const float*)d_in[5];
  const float* Wout  = (const float*)d_in[6];
  const float* bout  = (const float*)d_in[7];

  float* out_msg   = (float*)d_out;                       // [16][8192][512]
  float* out_masks = out_msg + (size_t)Ld * Bsz * Vd;     // [16][1][8192]
  float* out_lp    = out_masks + (size_t)Ld * Bsz;        // [8192]

  char* ws = (char*)d_ws;
  float* WihT  = (float*)ws;          ws += (size_t)Vd * G4 * 4;
  unsigned short* WhhHi = (unsigned short*)ws; ws += (size_t)G4 * Hd * 2;
  unsigned short* WhhLo = (unsigned short*)ws; ws += (size_t)G4 * Hd * 2;
  unsigned short* WoHi  = (unsigned short*)ws; ws += (size_t)Vd * Hd * 2;
  unsigned short* WoLo  = (unsigned short*)ws; ws += (size_t)Vd * Hd * 2;
  unsigned short* hhi0  = (unsigned short*)ws; ws += (size_t)Bsz * Hd * 2;
  unsigned short* hlo0  = (unsigned short*)ws; ws += (size_t)Bsz * Hd * 2;
  unsigned short* hhi1  = (unsigned short*)ws; ws += (size_t)Bsz * Hd * 2;
  unsigned short* hlo1  = (unsigned short*)ws; ws += (size_t)Bsz * Hd * 2;
  float* cbuf   = (float*)ws;  ws += (size_t)Bsz * Hd * 4;
  float* statM  = (float*)ws;  ws += (size_t)8 * Bsz * 4;
  float* statS  = (float*)ws;  ws += (size_t)8 * Bsz * 4;
  int*   statI  = (int*)ws;    ws += (size_t)8 * Bsz * 4;
  float* lpbuf  = (float*)ws;  ws += (size_t)Bsz * 4;
  float* mbuf   = (float*)ws;  ws += (size_t)Bsz * 4;
  int*   xidx   = (int*)ws;    ws += (size_t)Bsz * 4;

  k_transpose<<<dim3(Vd/32, G4/32), dim3(32,8), 0, stream>>>(Wih, WihT);
  k_split<<<(G4*Hd+255)/256, 256, 0, stream>>>(Whh,  WhhHi, WhhLo, G4*Hd);
  k_split<<<(Vd*Hd+255)/256, 256, 0, stream>>>(Wout, WoHi,  WoLo,  Vd*Hd);
  k_split<<<(Bsz*Hd+255)/256, 256, 0, stream>>>(enc_h, hhi0, hlo0, Bsz*Hd);

  for(int t=0; t<Ld; t++){
    const unsigned short* hih = (t & 1) ? hhi1 : hhi0;
    const unsigned short* hil = (t & 1) ? hlo1 : hlo0;
    unsigned short* hoh = (t & 1) ? hhi0 : hhi1;
    unsigned short* hol = (t & 1) ? hlo0 : hlo1;
    const float* ci = (t == 0) ? enc_c : cbuf;

    k_lstm_mfma<<<dim3(Bsz/128, Hd/32), 256, 0, stream>>>(
        hih, hil, ci, hoh, hol, cbuf, WhhHi, WhhLo, WihT, bih, bhh, xidx, t);
    k_logits_stats<<<dim3(Bsz/128, Vd/128), 256, 0, stream>>>(
        hoh, hol, WoHi, WoLo, bout, statM, statS, statI);
    k_merge<<<Bsz/32, 256, 0, stream>>>(statM, statS, statI,
                                        out_msg, out_masks, out_lp,
                                        lpbuf, mbuf, xidx, t);
  }
}

// Round 5
// 1807.562 us; speedup vs baseline: 1.1726x; 1.0011x over previous
//
#include <hip/hip_runtime.h>
#include <math.h>

#define Bsz 8192
#define Hd  512
#define Vd  512
#define Ld  16
#define G4  2048   // 4*Hd

using short8 = __attribute__((ext_vector_type(8))) short;
using f32x4  = __attribute__((ext_vector_type(4))) float;

__device__ __forceinline__ float sigm_f(float x){
  return __builtin_amdgcn_rcpf(1.0f + __expf(-x));
}
__device__ __forceinline__ float tanh_f(float x){
  return 1.0f - 2.0f * __builtin_amdgcn_rcpf(1.0f + __expf(2.0f * x));
}

// bf16 bit helpers (RNE)
__device__ __forceinline__ unsigned short f2bf(float f){
  unsigned int u = __float_as_uint(f);
  u = (u + 0x7fffu + ((u >> 16) & 1u)) >> 16;
  return (unsigned short)u;
}
__device__ __forceinline__ float bf2f(unsigned short b){
  return __uint_as_float(((unsigned int)b) << 16);
}

__device__ __forceinline__ void gl_lds16(const void* g, void* l){
  __builtin_amdgcn_global_load_lds((const __attribute__((address_space(1))) void*)g,
                                   (__attribute__((address_space(3))) void*)l, 16, 0, 0);
}

// ---------------------------------------------------------------------------
// Transpose W_ih (2048 x 512) -> W_ihT (512 x 2048): one-hot gather rows.
// ---------------------------------------------------------------------------
__global__ __launch_bounds__(256) void k_transpose(const float* __restrict__ in,
                                                   float* __restrict__ out){
  __shared__ float tile[32][33];
  const int tx = threadIdx.x, ty = threadIdx.y;
  const int v0 = blockIdx.x * 32, n0 = blockIdx.y * 32;
#pragma unroll
  for(int i=0;i<4;i++)
    tile[ty+i*8][tx] = in[(size_t)(n0+ty+i*8)*Vd + v0+tx];
  __syncthreads();
#pragma unroll
  for(int i=0;i<4;i++)
    out[(size_t)(v0+ty+i*8)*G4 + n0+tx] = tile[tx][ty+i*8];
}

// ---------------------------------------------------------------------------
// Split fp32 -> (bf16 hi, bf16 lo)
// ---------------------------------------------------------------------------
__global__ __launch_bounds__(256) void k_split(const float* __restrict__ src,
                                               unsigned short* __restrict__ hi,
                                               unsigned short* __restrict__ lo, int n){
  const int i = blockIdx.x*256 + threadIdx.x;
  if(i < n){
    const float x = src[i];
    const unsigned short h = f2bf(x);
    hi[i] = h;
    lo[i] = f2bf(x - bf2f(h));
  }
}

// ---------------------------------------------------------------------------
// Kernel A: fused LSTM step via MFMA (bf16x2, 3 products), swapped operands.
// Block tile: 128 batch x 64 j x 4 gates  -> grid 64x8 = 512 blocks
// = exactly 2 blocks/CU x 256 CU co-resident (no tail block-wave).
// Wave: 64 batch x 32 j x 4 gates; acc[g][jt][bt] = 32 f32x4 = 128 VGPR.
// ---------------------------------------------------------------------------
__global__ __launch_bounds__(256, 2) void k_lstm_mfma(
    const unsigned short* __restrict__ hh, const unsigned short* __restrict__ hl,
    const float* __restrict__ cin,
    unsigned short* __restrict__ hout_hi, unsigned short* __restrict__ hout_lo,
    float* __restrict__ cout,
    const unsigned short* __restrict__ Whh_hi, const unsigned short* __restrict__ Whh_lo,
    const float* __restrict__ WihT, const float* __restrict__ bih,
    const float* __restrict__ bhh, const int* __restrict__ xidx, int step)
{
  __shared__ unsigned short lds[24576];        // 48 KB
  unsigned short* Whi = lds;                   // 256 x 32 (gate-gathered W rows)
  unsigned short* Wlo = lds + 8192;
  unsigned short* Hhi = lds + 16384;           // 128 x 32 (batch rows)
  unsigned short* Hlo = lds + 20480;

  const int tid = threadIdx.x;
  const int wave = tid >> 6, lane = tid & 63;
  const int mb = blockIdx.x * 128;             // batch tile
  const int jb = blockIdx.y * 64;              // hidden-j tile
  const int b_wave = (wave & 1) * 64;
  const int j_wave = (wave >> 1) * 32;
  const int fr = lane & 15, q = lane >> 4;
  const int lr = lane >> 2, jj = lane & 3;

  // ---- prefetch (independent of GEMM): xidx + bias sums
  int xid[4];
  if(step > 0){
#pragma unroll
    for(int bt=0;bt<4;bt++)
      xid[bt] = xidx[mb + b_wave + bt*16 + fr];
  }
  float bsum[4][2][4];                         // [gate][jt][4]
#pragma unroll
  for(int g=0;g<4;g++)
#pragma unroll
    for(int jt=0;jt<2;jt++){
      const int j0 = jb + j_wave + jt*16 + q*4;
      float4 a = *(const float4*)&bih[g*Hd + j0];
      float4 b = *(const float4*)&bhh[g*Hd + j0];
      bsum[g][jt][0]=a.x+b.x; bsum[g][jt][1]=a.y+b.y;
      bsum[g][jt][2]=a.z+b.z; bsum[g][jt][3]=a.w+b.w;
    }

  f32x4 acc[4][2][4];                          // [gate][jt][bt]
#pragma unroll
  for(int g=0;g<4;g++)
#pragma unroll
    for(int jt=0;jt<2;jt++)
#pragma unroll
      for(int bt=0;bt<4;bt++) acc[g][jt][bt] = (f32x4){0.f,0.f,0.f,0.f};

  for(int k0=0; k0<Hd; k0+=32){
    // ---- staging: W 256 rows (wave's quarter: 64 rows), H 128 rows (32/wave)
#pragma unroll
    for(int p=0;p<4;p++){
      const int r = wave*64 + p*16 + lr;       // 0..255
      const int j = jj ^ ((r >> 1) & 3);
      const size_t ka = (size_t)k0 + j*8;
      const size_t wrow = (size_t)((r >> 6)*Hd + jb + (r & 63));
      gl_lds16(Whh_hi + wrow*Hd + ka, &Whi[(wave*64 + p*16)*32]);
      gl_lds16(Whh_lo + wrow*Hd + ka, &Wlo[(wave*64 + p*16)*32]);
    }
#pragma unroll
    for(int p=0;p<2;p++){
      const int r = wave*32 + p*16 + lr;       // 0..127
      const int j = jj ^ ((r >> 1) & 3);
      const size_t ka = (size_t)k0 + j*8;
      gl_lds16(hh + (size_t)(mb + r)*Hd + ka, &Hhi[(wave*32 + p*16)*32]);
      gl_lds16(hl + (size_t)(mb + r)*Hd + ka, &Hlo[(wave*32 + p*16)*32]);
    }
    __syncthreads();

    short8 hf[4], lf[4];
#pragma unroll
    for(int bt=0;bt<4;bt++){
      const int r = b_wave + bt*16 + fr;
      const int off = r*32 + ((q ^ ((r >> 1) & 3)) << 3);
      hf[bt] = *(const short8*)&Hhi[off];
      lf[bt] = *(const short8*)&Hlo[off];
    }
#pragma unroll
    for(int g=0;g<4;g++){
#pragma unroll
      for(int jt=0;jt<2;jt++){
        const int r = g*64 + j_wave + jt*16 + fr;
        const int off = r*32 + ((q ^ ((r >> 1) & 3)) << 3);
        const short8 wh = *(const short8*)&Whi[off];
        const short8 wl = *(const short8*)&Wlo[off];
#pragma unroll
        for(int bt=0;bt<4;bt++){
          acc[g][jt][bt] = __builtin_amdgcn_mfma_f32_16x16x32_bf16(wh, hf[bt], acc[g][jt][bt], 0,0,0);
          acc[g][jt][bt] = __builtin_amdgcn_mfma_f32_16x16x32_bf16(wh, lf[bt], acc[g][jt][bt], 0,0,0);
          acc[g][jt][bt] = __builtin_amdgcn_mfma_f32_16x16x32_bf16(wl, hf[bt], acc[g][jt][bt], 0,0,0);
        }
      }
    }
    __syncthreads();
  }

  // ---- epilogue: 4 batch x 2 jt x 4 contiguous j, all vectorized
#pragma unroll
  for(int bt=0;bt<4;bt++){
    const int b = mb + b_wave + bt*16 + fr;
#pragma unroll
    for(int jt=0;jt<2;jt++){
      const int j0 = jb + j_wave + jt*16 + q*4;
      const size_t idx = (size_t)b*Hd + j0;
      float gv[4][4];
#pragma unroll
      for(int g=0;g<4;g++)
#pragma unroll
        for(int r=0;r<4;r++) gv[g][r] = acc[g][jt][bt][r] + bsum[g][jt][r];
      if(step > 0){
        const float* grow = WihT + (size_t)xid[bt]*G4 + j0;
#pragma unroll
        for(int g=0;g<4;g++){
          float4 x = *(const float4*)&grow[g*Hd];
          gv[g][0]+=x.x; gv[g][1]+=x.y; gv[g][2]+=x.z; gv[g][3]+=x.w;
        }
      }
      float co[4];
      *(float4*)co = *(const float4*)&cin[idx];
      float cn[4];
      unsigned short hi4[4], lo4[4];
#pragma unroll
      for(int r=0;r<4;r++){
        const float I = sigm_f(gv[0][r]);
        const float F = sigm_f(gv[1][r]);
        const float G = tanh_f(gv[2][r]);
        const float O = sigm_f(gv[3][r]);
        cn[r] = F*co[r] + I*G;
        const float hn = O*tanh_f(cn[r]);
        const unsigned short hb = f2bf(hn);
        hi4[r] = hb;
        lo4[r] = f2bf(hn - bf2f(hb));
      }
      *(float4*)&cout[idx] = *(float4*)cn;
      *(short4*)&hout_hi[idx] = *(short4*)hi4;
      *(short4*)&hout_lo[idx] = *(short4*)lo4;
    }
  }
}

// ---------------------------------------------------------------------------
// Kernel B: logits stats (bf16x2, 3 products). 128x128 tile, no logits write:
// per-row (max, argmax, sumexp) over each 64-col slab -> stat buffers [8][B].
// Grid 256 blocks (under capacity, no tail).
// ---------------------------------------------------------------------------
__global__ __launch_bounds__(256) void k_logits_stats(
    const unsigned short* __restrict__ hh, const unsigned short* __restrict__ hl,
    const unsigned short* __restrict__ Wh, const unsigned short* __restrict__ Wl,
    const float* __restrict__ bout,
    float* __restrict__ statM, float* __restrict__ statS, int* __restrict__ statI)
{
  __shared__ unsigned short lds[16384];
  unsigned short* Ahi = lds;
  unsigned short* Alo = lds + 4096;
  unsigned short* Bhi = lds + 8192;
  unsigned short* Blo = lds + 12288;

  const int tid = threadIdx.x;
  const int wave = tid >> 6, lane = tid & 63;
  const int mb = blockIdx.x * 128;
  const int vb = blockIdx.y * 128;
  const int m_wave = (wave & 1) * 64;
  const int n_wave = (wave >> 1) * 64;
  const int fr = lane & 15, q = lane >> 4;
  const int lr = lane >> 2, jj = lane & 3;

  f32x4 acc[4][4];                             // [nt][mt]
#pragma unroll
  for(int nt=0;nt<4;nt++)
#pragma unroll
    for(int mt=0;mt<4;mt++) acc[nt][mt] = (f32x4){0.f,0.f,0.f,0.f};

  for(int k0=0; k0<Hd; k0+=32){
#pragma unroll
    for(int p=0;p<2;p++){
      const int s = wave*2 + p;
      const int r = s*16 + lr;
      const int j = jj ^ ((r >> 1) & 3);
      const size_t ka = (size_t)k0 + j*8;
      gl_lds16(hh + (size_t)(mb + r)*Hd + ka, &Ahi[s*512]);
      gl_lds16(hl + (size_t)(mb + r)*Hd + ka, &Alo[s*512]);
      gl_lds16(Wh + (size_t)(vb + r)*Hd + ka, &Bhi[s*512]);
      gl_lds16(Wl + (size_t)(vb + r)*Hd + ka, &Blo[s*512]);
    }
    __syncthreads();

    short8 ah[4], al[4], bh[4], bl[4];
#pragma unroll
    for(int mt=0;mt<4;mt++){
      const int r = m_wave + mt*16 + fr;
      const int off = r*32 + ((q ^ ((r >> 1) & 3)) << 3);
      ah[mt] = *(const short8*)&Ahi[off];
      al[mt] = *(const short8*)&Alo[off];
    }
#pragma unroll
    for(int nt=0;nt<4;nt++){
      const int r = n_wave + nt*16 + fr;
      const int off = r*32 + ((q ^ ((r >> 1) & 3)) << 3);
      bh[nt] = *(const short8*)&Bhi[off];
      bl[nt] = *(const short8*)&Blo[off];
    }
#pragma unroll
    for(int nt=0;nt<4;nt++)
#pragma unroll
      for(int mt=0;mt<4;mt++){
        acc[nt][mt] = __builtin_amdgcn_mfma_f32_16x16x32_bf16(ah[mt], bh[nt], acc[nt][mt], 0,0,0);
        acc[nt][mt] = __builtin_amdgcn_mfma_f32_16x16x32_bf16(ah[mt], bl[nt], acc[nt][mt], 0,0,0);
        acc[nt][mt] = __builtin_amdgcn_mfma_f32_16x16x32_bf16(al[mt], bh[nt], acc[nt][mt], 0,0,0);
      }
    __syncthreads();
  }

  const int slab = blockIdx.y*2 + (wave >> 1);
  float bo[4];
  int vv[4];
#pragma unroll
  for(int nt=0;nt<4;nt++){
    vv[nt] = vb + n_wave + nt*16 + fr;
    bo[nt] = bout[vv[nt]];
  }
#pragma unroll
  for(int mt=0;mt<4;mt++){
#pragma unroll
    for(int reg=0;reg<4;reg++){
      float vmax = acc[0][mt][reg] + bo[0];
      int   imax = vv[0];
#pragma unroll
      for(int nt=1;nt<4;nt++){
        const float v = acc[nt][mt][reg] + bo[nt];
        if(v > vmax || (v == vmax && vv[nt] < imax)){ vmax = v; imax = vv[nt]; }
      }
#pragma unroll
      for(int off=1; off<16; off<<=1){
        const float vo = __shfl_xor(vmax, off);
        const int   io = __shfl_xor(imax, off);
        if(vo > vmax || (vo == vmax && io < imax)){ vmax = vo; imax = io; }
      }
      float s = 0.0f;
#pragma unroll
      for(int nt=0;nt<4;nt++) s += __expf(acc[nt][mt][reg] + bo[nt] - vmax);
#pragma unroll
      for(int off=1; off<16; off<<=1) s += __shfl_xor(s, off);
      if(fr == 0){
        const int m = mb + m_wave + mt*16 + q*4 + reg;
        statM[(size_t)slab*Bsz + m] = vmax;
        statS[(size_t)slab*Bsz + m] = s;
        statI[(size_t)slab*Bsz + m] = imax;
      }
    }
  }
}

// ---------------------------------------------------------------------------
// Kernel C: merge 8 slabs per row; write masks/lp/xidx + one-hot message.
// ---------------------------------------------------------------------------
__global__ __launch_bounds__(256) void k_merge(
    const float* __restrict__ statM, const float* __restrict__ statS,
    const int* __restrict__ statI,
    float* __restrict__ msg, float* __restrict__ masks_out,
    float* __restrict__ lp_out, float* __restrict__ lpbuf,
    float* __restrict__ mbuf, int* __restrict__ xidx, int step)
{
  __shared__ int gI[32];
  const int tid = threadIdx.x;
  const int mb = blockIdx.x * 32;

  if(tid < 32){
    const int row = mb + tid;
    float gm = statM[row]; int gi = statI[row];
#pragma unroll
    for(int s=1;s<8;s++){
      const float m = statM[(size_t)s*Bsz + row];
      if(m > gm){ gm = m; gi = statI[(size_t)s*Bsz + row]; }
    }
    float tot = 0.0f;
#pragma unroll
    for(int s=0;s<8;s++)
      tot += statS[(size_t)s*Bsz + row] * __expf(statM[(size_t)s*Bsz + row] - gm);
    const float logp = -__logf(tot);
    const float mo  = (step == 0) ? 1.0f : mbuf[row];
    const float lpo = (step == 0) ? 0.0f : lpbuf[row];
    const float lpn = lpo + logp * mo;
    masks_out[(size_t)step * Bsz + row] = mo;
    lp_out[row] = lpn;
    lpbuf[row]  = lpn;
    mbuf[row]   = mo * ((gi == Vd-1) ? 0.0f : 1.0f);
    xidx[row]   = gi;
    gI[tid] = gi;
  }
  __syncthreads();

  const int r  = tid >> 3;
  const int c8 = tid & 7;
  const int gi = gI[r];
  float* mrow = msg + ((size_t)step * Bsz + mb + r) * Vd;
#pragma unroll
  for(int i=0;i<16;i++){
    const int c = (i*8 + c8) * 4;
    float4 v;
    v.x = (c   == gi) ? 1.0f : 0.0f;
    v.y = (c+1 == gi) ? 1.0f : 0.0f;
    v.z = (c+2 == gi) ? 1.0f : 0.0f;
    v.w = (c+3 == gi) ? 1.0f : 0.0f;
    *(float4*)&mrow[c] = v;
  }
}

// ---------------------------------------------------------------------------
extern "C" void kernel_launch(void* const* d_in, const int* in_sizes, int n_in,
                              void* d_out, int out_size, void* d_ws, size_t ws_size,
                              hipStream_t stream) {
  const float* enc_h = (const float*)d_in[0];
  const float* enc_c = (const float*)d_in[1];
  const float* Wih   = (const float*)d_in[2];
  const float* Whh   = (const float*)d_in[3];
  const float* bih   = (const float*)d_in[4];
  const float* bhh   = (const float*)d_in[5];
  const float* Wout  = (const float*)d_in[6];
  const float* bout  = (const float*)d_in[7];

  float* out_msg   = (float*)d_out;                       // [16][8192][512]
  float* out_masks = out_msg + (size_t)Ld * Bsz * Vd;     // [16][1][8192]
  float* out_lp    = out_masks + (size_t)Ld * Bsz;        // [8192]

  char* ws = (char*)d_ws;
  float* WihT  = (float*)ws;          ws += (size_t)Vd * G4 * 4;
  unsigned short* WhhHi = (unsigned short*)ws; ws += (size_t)G4 * Hd * 2;
  unsigned short* WhhLo = (unsigned short*)ws; ws += (size_t)G4 * Hd * 2;
  unsigned short* WoHi  = (unsigned short*)ws; ws += (size_t)Vd * Hd * 2;
  unsigned short* WoLo  = (unsigned short*)ws; ws += (size_t)Vd * Hd * 2;
  unsigned short* hhi0  = (unsigned short*)ws; ws += (size_t)Bsz * Hd * 2;
  unsigned short* hlo0  = (unsigned short*)ws; ws += (size_t)Bsz * Hd * 2;
  unsigned short* hhi1  = (unsigned short*)ws; ws += (size_t)Bsz * Hd * 2;
  unsigned short* hlo1  = (unsigned short*)ws; ws += (size_t)Bsz * Hd * 2;
  float* cbuf   = (float*)ws;  ws += (size_t)Bsz * Hd * 4;
  float* statM  = (float*)ws;  ws += (size_t)8 * Bsz * 4;
  float* statS  = (float*)ws;  ws += (size_t)8 * Bsz * 4;
  int*   statI  = (int*)ws;    ws += (size_t)8 * Bsz * 4;
  float* lpbuf  = (float*)ws;  ws += (size_t)Bsz * 4;
  float* mbuf   = (float*)ws;  ws += (size_t)Bsz * 4;
  int*   xidx   = (int*)ws;    ws += (size_t)Bsz * 4;

  k_transpose<<<dim3(Vd/32, G4/32), dim3(32,8), 0, stream>>>(Wih, WihT);
  k_split<<<(G4*Hd+255)/256, 256, 0, stream>>>(Whh,  WhhHi, WhhLo, G4*Hd);
  k_split<<<(Vd*Hd+255)/256, 256, 0, stream>>>(Wout, WoHi,  WoLo,  Vd*Hd);
  k_split<<<(Bsz*Hd+255)/256, 256, 0, stream>>>(enc_h, hhi0, hlo0, Bsz*Hd);

  for(int t=0; t<Ld; t++){
    const unsigned short* hih = (t & 1) ? hhi1 : hhi0;
    const unsigned short* hil = (t & 1) ? hlo1 : hlo0;
    unsigned short* hoh = (t & 1) ? hhi0 : hhi1;
    unsigned short* hol = (t & 1) ? hlo0 : hlo1;
    const float* ci = (t == 0) ? enc_c : cbuf;

    k_lstm_mfma<<<dim3(Bsz/128, Hd/64), 256, 0, stream>>>(
        hih, hil, ci, hoh, hol, cbuf, WhhHi, WhhLo, WihT, bih, bhh, xidx, t);
    k_logits_stats<<<dim3(Bsz/128, Vd/128), 256, 0, stream>>>(
        hoh, hol, WoHi, WoLo, bout, statM, statS, statI);
    k_merge<<<Bsz/32, 256, 0, stream>>>(statM, statS, statI,
                                        out_msg, out_masks, out_lp,
                                        lpbuf, mbuf, xidx, t);
  }
}

// Round 6
// 1615.544 us; speedup vs baseline: 1.3120x; 1.1189x over previous
//
#include <hip/hip_runtime.h>
#include <math.h>

#define Bsz 8192
#define Hd  512
#define Vd  512
#define Ld  16
#define G4  2048   // 4*Hd

using short8 = __attribute__((ext_vector_type(8))) short;
using f32x4  = __attribute__((ext_vector_type(4))) float;

__device__ __forceinline__ float sigm_f(float x){
  return __builtin_amdgcn_rcpf(1.0f + __expf(-x));
}
__device__ __forceinline__ float tanh_f(float x){
  return 1.0f - 2.0f * __builtin_amdgcn_rcpf(1.0f + __expf(2.0f * x));
}

// bf16 bit helpers (RNE)
__device__ __forceinline__ unsigned short f2bf(float f){
  unsigned int u = __float_as_uint(f);
  u = (u + 0x7fffu + ((u >> 16) & 1u)) >> 16;
  return (unsigned short)u;
}
__device__ __forceinline__ float bf2f(unsigned short b){
  return __uint_as_float(((unsigned int)b) << 16);
}

__device__ __forceinline__ void gl_lds16(const void* g, void* l){
  __builtin_amdgcn_global_load_lds((const __attribute__((address_space(1))) void*)g,
                                   (__attribute__((address_space(3))) void*)l, 16, 0, 0);
}

// ---------------------------------------------------------------------------
// Transpose W_ih (2048 x 512) -> W_ihT (512 x 2048): one-hot gather rows.
// ---------------------------------------------------------------------------
__global__ __launch_bounds__(256) void k_transpose(const float* __restrict__ in,
                                                   float* __restrict__ out){
  __shared__ float tile[32][33];
  const int tx = threadIdx.x, ty = threadIdx.y;
  const int v0 = blockIdx.x * 32, n0 = blockIdx.y * 32;
#pragma unroll
  for(int i=0;i<4;i++)
    tile[ty+i*8][tx] = in[(size_t)(n0+ty+i*8)*Vd + v0+tx];
  __syncthreads();
#pragma unroll
  for(int i=0;i<4;i++)
    out[(size_t)(v0+ty+i*8)*G4 + n0+tx] = tile[tx][ty+i*8];
}

// ---------------------------------------------------------------------------
// Split fp32 -> (bf16 hi, bf16 lo)
// ---------------------------------------------------------------------------
__global__ __launch_bounds__(256) void k_split(const float* __restrict__ src,
                                               unsigned short* __restrict__ hi,
                                               unsigned short* __restrict__ lo, int n){
  const int i = blockIdx.x*256 + threadIdx.x;
  if(i < n){
    const float x = src[i];
    const unsigned short h = f2bf(x);
    hi[i] = h;
    lo[i] = f2bf(x - bf2f(h));
  }
}

// ---------------------------------------------------------------------------
// Kernel A: fused LSTM step via MFMA (bf16x2, 3 products), swapped operands,
// DOUBLE-BUFFERED LDS: chunk k+1's global_load_lds issues before chunk k's
// MFMAs -> barrier vmcnt drain overlapped by compute. 1 barrier/iter.
// Block tile: 128 batch x 32 j x 4 gates; 64 KB LDS; 2 blocks/CU; grid 1024.
// ---------------------------------------------------------------------------
__global__ __launch_bounds__(256, 2) void k_lstm_mfma(
    const unsigned short* __restrict__ hh, const unsigned short* __restrict__ hl,
    const float* __restrict__ cin,
    unsigned short* __restrict__ hout_hi, unsigned short* __restrict__ hout_lo,
    float* __restrict__ cout,
    const unsigned short* __restrict__ Whh_hi, const unsigned short* __restrict__ Whh_lo,
    const float* __restrict__ WihT, const float* __restrict__ bih,
    const float* __restrict__ bhh, const int* __restrict__ xidx, int step)
{
  __shared__ unsigned short lds[2][16384];     // 2 x 32 KB
  const int tid = threadIdx.x;
  const int wave = tid >> 6, lane = tid & 63;
  const int mb = blockIdx.x * 128;             // batch tile
  const int jb = blockIdx.y * 32;              // hidden-j tile
  const int b_wave = (wave & 1) * 64;
  const int j_wave = (wave >> 1) * 16;
  const int fr = lane & 15, q = lane >> 4;
  const int lr = lane >> 2, jj = lane & 3;

  // ---- staging helper: chunk at k0 -> buffer bsel
  auto stage = [&](int k0, int bsel){
    unsigned short* Whi = lds[bsel];
    unsigned short* Wlo = lds[bsel] + 4096;
    unsigned short* Hhi = lds[bsel] + 8192;
    unsigned short* Hlo = lds[bsel] + 12288;
#pragma unroll
    for(int p=0;p<2;p++){
      const int s = wave*2 + p;
      const int r = s*16 + lr;                 // tile row 0..127
      const int j = jj ^ ((r >> 1) & 3);
      const size_t ka = (size_t)k0 + j*8;
      const size_t wrow = (size_t)((r >> 5)*Hd + jb + (r & 31));
      gl_lds16(Whh_hi + wrow*Hd + ka, &Whi[s*512]);
      gl_lds16(Whh_lo + wrow*Hd + ka, &Wlo[s*512]);
      gl_lds16(hh + (size_t)(mb + r)*Hd + ka, &Hhi[s*512]);
      gl_lds16(hl + (size_t)(mb + r)*Hd + ka, &Hlo[s*512]);
    }
  };

  stage(0, 0);                                 // prologue: chunk 0

  // ---- prefetch (independent of GEMM): xidx + bias sums
  int xid[4];
  if(step > 0){
#pragma unroll
    for(int bt=0;bt<4;bt++)
      xid[bt] = xidx[mb + b_wave + bt*16 + fr];
  }
  const int j0 = jb + j_wave + q*4;            // 4 contiguous j per thread
  float bsum[4][4];
#pragma unroll
  for(int g=0;g<4;g++){
    float4 a = *(const float4*)&bih[g*Hd + j0];
    float4 b = *(const float4*)&bhh[g*Hd + j0];
    bsum[g][0]=a.x+b.x; bsum[g][1]=a.y+b.y; bsum[g][2]=a.z+b.z; bsum[g][3]=a.w+b.w;
  }

  f32x4 acc[4][4];                             // [gate][bt]
#pragma unroll
  for(int g=0;g<4;g++)
#pragma unroll
    for(int bt=0;bt<4;bt++) acc[g][bt] = (f32x4){0.f,0.f,0.f,0.f};

  for(int kc=0; kc<16; kc++){
    __syncthreads();                           // buf[kc&1] staged; prev reads done
    if(kc < 15) stage((kc+1)*32, (kc+1)&1);    // prefetch next chunk NOW

    const unsigned short* Whi = lds[kc&1];
    const unsigned short* Wlo = lds[kc&1] + 4096;
    const unsigned short* Hhi = lds[kc&1] + 8192;
    const unsigned short* Hlo = lds[kc&1] + 12288;

    short8 wh[4], wl[4], hf[4], lf[4];
#pragma unroll
    for(int g=0;g<4;g++){
      const int r = g*32 + j_wave + fr;
      const int off = r*32 + ((q ^ ((r >> 1) & 3)) << 3);
      wh[g] = *(const short8*)&Whi[off];
      wl[g] = *(const short8*)&Wlo[off];
    }
#pragma unroll
    for(int bt=0;bt<4;bt++){
      const int r = b_wave + bt*16 + fr;
      const int off = r*32 + ((q ^ ((r >> 1) & 3)) << 3);
      hf[bt] = *(const short8*)&Hhi[off];
      lf[bt] = *(const short8*)&Hlo[off];
    }
#pragma unroll
    for(int g=0;g<4;g++)
#pragma unroll
      for(int bt=0;bt<4;bt++){
        acc[g][bt] = __builtin_amdgcn_mfma_f32_16x16x32_bf16(wh[g], hf[bt], acc[g][bt], 0,0,0);
        acc[g][bt] = __builtin_amdgcn_mfma_f32_16x16x32_bf16(wh[g], lf[bt], acc[g][bt], 0,0,0);
        acc[g][bt] = __builtin_amdgcn_mfma_f32_16x16x32_bf16(wl[g], hf[bt], acc[g][bt], 0,0,0);
      }
  }

  // ---- epilogue: 4 batch positions x 4 contiguous j, all vectorized
#pragma unroll
  for(int bt=0;bt<4;bt++){
    const int b = mb + b_wave + bt*16 + fr;
    const size_t idx = (size_t)b*Hd + j0;
    float gv[4][4];
#pragma unroll
    for(int g=0;g<4;g++)
#pragma unroll
      for(int r=0;r<4;r++) gv[g][r] = acc[g][bt][r] + bsum[g][r];
    if(step > 0){
      const float* grow = WihT + (size_t)xid[bt]*G4 + j0;
#pragma unroll
      for(int g=0;g<4;g++){
        float4 x = *(const float4*)&grow[g*Hd];
        gv[g][0]+=x.x; gv[g][1]+=x.y; gv[g][2]+=x.z; gv[g][3]+=x.w;
      }
    }
    float co[4];
    *(float4*)co = *(const float4*)&cin[idx];
    float cn[4];
    unsigned short hi4[4], lo4[4];
#pragma unroll
    for(int r=0;r<4;r++){
      const float I = sigm_f(gv[0][r]);
      const float F = sigm_f(gv[1][r]);
      const float G = tanh_f(gv[2][r]);
      const float O = sigm_f(gv[3][r]);
      cn[r] = F*co[r] + I*G;
      const float hn = O*tanh_f(cn[r]);
      const unsigned short hb = f2bf(hn);
      hi4[r] = hb;
      lo4[r] = f2bf(hn - bf2f(hb));
    }
    *(float4*)&cout[idx] = *(float4*)cn;
    *(short4*)&hout_hi[idx] = *(short4*)hi4;
    *(short4*)&hout_lo[idx] = *(short4*)lo4;
  }
}

// ---------------------------------------------------------------------------
// Kernel B: logits stats (bf16x2, 3 products), DOUBLE-BUFFERED like A.
// 128x128 tile; per-row (max, argmax, sumexp) per 64-col slab -> stat bufs.
// ---------------------------------------------------------------------------
__global__ __launch_bounds__(256, 2) void k_logits_stats(
    const unsigned short* __restrict__ hh, const unsigned short* __restrict__ hl,
    const unsigned short* __restrict__ Wh, const unsigned short* __restrict__ Wl,
    const float* __restrict__ bout,
    float* __restrict__ statM, float* __restrict__ statS, int* __restrict__ statI)
{
  __shared__ unsigned short lds[2][16384];
  const int tid = threadIdx.x;
  const int wave = tid >> 6, lane = tid & 63;
  const int mb = blockIdx.x * 128;
  const int vb = blockIdx.y * 128;
  const int m_wave = (wave & 1) * 64;
  const int n_wave = (wave >> 1) * 64;
  const int fr = lane & 15, q = lane >> 4;
  const int lr = lane >> 2, jj = lane & 3;

  auto stage = [&](int k0, int bsel){
    unsigned short* Ahi = lds[bsel];
    unsigned short* Alo = lds[bsel] + 4096;
    unsigned short* Bhi = lds[bsel] + 8192;
    unsigned short* Blo = lds[bsel] + 12288;
#pragma unroll
    for(int p=0;p<2;p++){
      const int s = wave*2 + p;
      const int r = s*16 + lr;
      const int j = jj ^ ((r >> 1) & 3);
      const size_t ka = (size_t)k0 + j*8;
      gl_lds16(hh + (size_t)(mb + r)*Hd + ka, &Ahi[s*512]);
      gl_lds16(hl + (size_t)(mb + r)*Hd + ka, &Alo[s*512]);
      gl_lds16(Wh + (size_t)(vb + r)*Hd + ka, &Bhi[s*512]);
      gl_lds16(Wl + (size_t)(vb + r)*Hd + ka, &Blo[s*512]);
    }
  };

  stage(0, 0);

  f32x4 acc[4][4];                             // [nt][mt]
#pragma unroll
  for(int nt=0;nt<4;nt++)
#pragma unroll
    for(int mt=0;mt<4;mt++) acc[nt][mt] = (f32x4){0.f,0.f,0.f,0.f};

  for(int kc=0; kc<16; kc++){
    __syncthreads();
    if(kc < 15) stage((kc+1)*32, (kc+1)&1);

    const unsigned short* Ahi = lds[kc&1];
    const unsigned short* Alo = lds[kc&1] + 4096;
    const unsigned short* Bhi = lds[kc&1] + 8192;
    const unsigned short* Blo = lds[kc&1] + 12288;

    short8 ah[4], al[4], bh[4], bl[4];
#pragma unroll
    for(int mt=0;mt<4;mt++){
      const int r = m_wave + mt*16 + fr;
      const int off = r*32 + ((q ^ ((r >> 1) & 3)) << 3);
      ah[mt] = *(const short8*)&Ahi[off];
      al[mt] = *(const short8*)&Alo[off];
    }
#pragma unroll
    for(int nt=0;nt<4;nt++){
      const int r = n_wave + nt*16 + fr;
      const int off = r*32 + ((q ^ ((r >> 1) & 3)) << 3);
      bh[nt] = *(const short8*)&Bhi[off];
      bl[nt] = *(const short8*)&Blo[off];
    }
#pragma unroll
    for(int nt=0;nt<4;nt++)
#pragma unroll
      for(int mt=0;mt<4;mt++){
        acc[nt][mt] = __builtin_amdgcn_mfma_f32_16x16x32_bf16(ah[mt], bh[nt], acc[nt][mt], 0,0,0);
        acc[nt][mt] = __builtin_amdgcn_mfma_f32_16x16x32_bf16(ah[mt], bl[nt], acc[nt][mt], 0,0,0);
        acc[nt][mt] = __builtin_amdgcn_mfma_f32_16x16x32_bf16(al[mt], bh[nt], acc[nt][mt], 0,0,0);
      }
  }

  const int slab = blockIdx.y*2 + (wave >> 1);
  float bo[4];
  int vv[4];
#pragma unroll
  for(int nt=0;nt<4;nt++){
    vv[nt] = vb + n_wave + nt*16 + fr;
    bo[nt] = bout[vv[nt]];
  }
#pragma unroll
  for(int mt=0;mt<4;mt++){
#pragma unroll
    for(int reg=0;reg<4;reg++){
      float vmax = acc[0][mt][reg] + bo[0];
      int   imax = vv[0];
#pragma unroll
      for(int nt=1;nt<4;nt++){
        const float v = acc[nt][mt][reg] + bo[nt];
        if(v > vmax || (v == vmax && vv[nt] < imax)){ vmax = v; imax = vv[nt]; }
      }
#pragma unroll
      for(int off=1; off<16; off<<=1){
        const float vo = __shfl_xor(vmax, off);
        const int   io = __shfl_xor(imax, off);
        if(vo > vmax || (vo == vmax && io < imax)){ vmax = vo; imax = io; }
      }
      float s = 0.0f;
#pragma unroll
      for(int nt=0;nt<4;nt++) s += __expf(acc[nt][mt][reg] + bo[nt] - vmax);
#pragma unroll
      for(int off=1; off<16; off<<=1) s += __shfl_xor(s, off);
      if(fr == 0){
        const int m = mb + m_wave + mt*16 + q*4 + reg;
        statM[(size_t)slab*Bsz + m] = vmax;
        statS[(size_t)slab*Bsz + m] = s;
        statI[(size_t)slab*Bsz + m] = imax;
      }
    }
  }
}

// ---------------------------------------------------------------------------
// Kernel C: merge 8 slabs per row; write masks/lp/xidx + one-hot message.
// ---------------------------------------------------------------------------
__global__ __launch_bounds__(256) void k_merge(
    const float* __restrict__ statM, const float* __restrict__ statS,
    const int* __restrict__ statI,
    float* __restrict__ msg, float* __restrict__ masks_out,
    float* __restrict__ lp_out, float* __restrict__ lpbuf,
    float* __restrict__ mbuf, int* __restrict__ xidx, int step)
{
  __shared__ int gI[32];
  const int tid = threadIdx.x;
  const int mb = blockIdx.x * 32;

  if(tid < 32){
    const int row = mb + tid;
    float gm = statM[row]; int gi = statI[row];
#pragma unroll
    for(int s=1;s<8;s++){
      const float m = statM[(size_t)s*Bsz + row];
      if(m > gm){ gm = m; gi = statI[(size_t)s*Bsz + row]; }
    }
    float tot = 0.0f;
#pragma unroll
    for(int s=0;s<8;s++)
      tot += statS[(size_t)s*Bsz + row] * __expf(statM[(size_t)s*Bsz + row] - gm);
    const float logp = -__logf(tot);
    const float mo  = (step == 0) ? 1.0f : mbuf[row];
    const float lpo = (step == 0) ? 0.0f : lpbuf[row];
    const float lpn = lpo + logp * mo;
    masks_out[(size_t)step * Bsz + row] = mo;
    lp_out[row] = lpn;
    lpbuf[row]  = lpn;
    mbuf[row]   = mo * ((gi == Vd-1) ? 0.0f : 1.0f);
    xidx[row]   = gi;
    gI[tid] = gi;
  }
  __syncthreads();

  const int r  = tid >> 3;
  const int c8 = tid & 7;
  const int gi = gI[r];
  float* mrow = msg + ((size_t)step * Bsz + mb + r) * Vd;
#pragma unroll
  for(int i=0;i<16;i++){
    const int c = (i*8 + c8) * 4;
    float4 v;
    v.x = (c   == gi) ? 1.0f : 0.0f;
    v.y = (c+1 == gi) ? 1.0f : 0.0f;
    v.z = (c+2 == gi) ? 1.0f : 0.0f;
    v.w = (c+3 == gi) ? 1.0f : 0.0f;
    *(float4*)&mrow[c] = v;
  }
}

// ---------------------------------------------------------------------------
extern "C" void kernel_launch(void* const* d_in, const int* in_sizes, int n_in,
                              void* d_out, int out_size, void* d_ws, size_t ws_size,
                              hipStream_t stream) {
  const float* enc_h = (const float*)d_in[0];
  const float* enc_c = (const float*)d_in[1];
  const float* Wih   = (const float*)d_in[2];
  const float* Whh   = (const float*)d_in[3];
  const float* bih   = (const float*)d_in[4];
  const float* bhh   = (const float*)d_in[5];
  const float* Wout  = (const float*)d_in[6];
  const float* bout  = (const float*)d_in[7];

  float* out_msg   = (float*)d_out;                       // [16][8192][512]
  float* out_masks = out_msg + (size_t)Ld * Bsz * Vd;     // [16][1][8192]
  float* out_lp    = out_masks + (size_t)Ld * Bsz;        // [8192]

  char* ws = (char*)d_ws;
  float* WihT  = (float*)ws;          ws += (size_t)Vd * G4 * 4;
  unsigned short* WhhHi = (unsigned short*)ws; ws += (size_t)G4 * Hd * 2;
  unsigned short* WhhLo = (unsigned short*)ws; ws += (size_t)G4 * Hd * 2;
  unsigned short* WoHi  = (unsigned short*)ws; ws += (size_t)Vd * Hd * 2;
  unsigned short* WoLo  = (unsigned short*)ws; ws += (size_t)Vd * Hd * 2;
  unsigned short* hhi0  = (unsigned short*)ws; ws += (size_t)Bsz * Hd * 2;
  unsigned short* hlo0  = (unsigned short*)ws; ws += (size_t)Bsz * Hd * 2;
  unsigned short* hhi1  = (unsigned short*)ws; ws += (size_t)Bsz * Hd * 2;
  unsigned short* hlo1  = (unsigned short*)ws; ws += (size_t)Bsz * Hd * 2;
  float* cbuf   = (float*)ws;  ws += (size_t)Bsz * Hd * 4;
  float* statM  = (float*)ws;  ws += (size_t)8 * Bsz * 4;
  float* statS  = (float*)ws;  ws += (size_t)8 * Bsz * 4;
  int*   statI  = (int*)ws;    ws += (size_t)8 * Bsz * 4;
  float* lpbuf  = (float*)ws;  ws += (size_t)Bsz * 4;
  float* mbuf   = (float*)ws;  ws += (size_t)Bsz * 4;
  int*   xidx   = (int*)ws;    ws += (size_t)Bsz * 4;

  k_transpose<<<dim3(Vd/32, G4/32), dim3(32,8), 0, stream>>>(Wih, WihT);
  k_split<<<(G4*Hd+255)/256, 256, 0, stream>>>(Whh,  WhhHi, WhhLo, G4*Hd);
  k_split<<<(Vd*Hd+255)/256, 256, 0, stream>>>(Wout, WoHi,  WoLo,  Vd*Hd);
  k_split<<<(Bsz*Hd+255)/256, 256, 0, stream>>>(enc_h, hhi0, hlo0, Bsz*Hd);

  for(int t=0; t<Ld; t++){
    const unsigned short* hih = (t & 1) ? hhi1 : hhi0;
    const unsigned short* hil = (t & 1) ? hlo1 : hlo0;
    unsigned short* hoh = (t & 1) ? hhi0 : hhi1;
    unsigned short* hol = (t & 1) ? hlo0 : hlo1;
    const float* ci = (t == 0) ? enc_c : cbuf;

    k_lstm_mfma<<<dim3(Bsz/128, Hd/32), 256, 0, stream>>>(
        hih, hil, ci, hoh, hol, cbuf, WhhHi, WhhLo, WihT, bih, bhh, xidx, t);
    k_logits_stats<<<dim3(Bsz/128, Vd/128), 256, 0, stream>>>(
        hoh, hol, WoHi, WoLo, bout, statM, statS, statI);
    k_merge<<<Bsz/32, 256, 0, stream>>>(statM, statS, statI,
                                        out_msg, out_masks, out_lp,
                                        lpbuf, mbuf, xidx, t);
  }
}

// Round 7
// 1272.994 us; speedup vs baseline: 1.6650x; 1.2691x over previous
//
#include <hip/hip_runtime.h>
#include <math.h>

#define Bsz 8192
#define Hd  512
#define Vd  512
#define Ld  16
#define G4  2048   // 4*Hd

using short8 = __attribute__((ext_vector_type(8))) short;
using f32x4  = __attribute__((ext_vector_type(4))) float;
using int4v  = __attribute__((ext_vector_type(4))) int;

__device__ __forceinline__ float sigm_f(float x){
  return __builtin_amdgcn_rcpf(1.0f + __expf(-x));
}
__device__ __forceinline__ float tanh_f(float x){
  return 1.0f - 2.0f * __builtin_amdgcn_rcpf(1.0f + __expf(2.0f * x));
}

// bf16 bit helpers (RNE)
__device__ __forceinline__ unsigned short f2bf(float f){
  unsigned int u = __float_as_uint(f);
  u = (u + 0x7fffu + ((u >> 16) & 1u)) >> 16;
  return (unsigned short)u;
}
__device__ __forceinline__ float bf2f(unsigned short b){
  return __uint_as_float(((unsigned int)b) << 16);
}

// int16 -> signed i8 pair: q = 256*a + b, a,b in [-128,127]
__device__ __forceinline__ void i16split(float x, float S, signed char& a, signed char& b){
  int q = (int)rintf(x * S);
  q = min(max(q, -32640), 32639);
  const int ah = (q + 128) >> 8;
  a = (signed char)ah;
  b = (signed char)(q - (ah << 8));
}

__device__ __forceinline__ void gl_lds16(const void* g, void* l){
  __builtin_amdgcn_global_load_lds((const __attribute__((address_space(1))) void*)g,
                                   (__attribute__((address_space(3))) void*)l, 16, 0, 0);
}

// reconstruction constants: value = (65536*acc1 + 256*acc2) / (2^19 * 32767)
#define C1I (65536.0f / (524288.0f * 32767.0f))
#define C2I (  256.0f / (524288.0f * 32767.0f))

// ---------------------------------------------------------------------------
// Transpose W_ih (2048 x 512) -> W_ihT (512 x 2048): one-hot gather rows.
// ---------------------------------------------------------------------------
__global__ __launch_bounds__(256) void k_transpose(const float* __restrict__ in,
                                                   float* __restrict__ out){
  __shared__ float tile[32][33];
  const int tx = threadIdx.x, ty = threadIdx.y;
  const int v0 = blockIdx.x * 32, n0 = blockIdx.y * 32;
#pragma unroll
  for(int i=0;i<4;i++)
    tile[ty+i*8][tx] = in[(size_t)(n0+ty+i*8)*Vd + v0+tx];
  __syncthreads();
#pragma unroll
  for(int i=0;i<4;i++)
    out[(size_t)(v0+ty+i*8)*G4 + n0+tx] = tile[tx][ty+i*8];
}

// ---------------------------------------------------------------------------
// Split fp32 -> (bf16 hi, bf16 lo)   [step-0 path only]
// ---------------------------------------------------------------------------
__global__ __launch_bounds__(256) void k_split(const float* __restrict__ src,
                                               unsigned short* __restrict__ hi,
                                               unsigned short* __restrict__ lo, int n){
  const int i = blockIdx.x*256 + threadIdx.x;
  if(i < n){
    const float x = src[i];
    const unsigned short h = f2bf(x);
    hi[i] = h;
    lo[i] = f2bf(x - bf2f(h));
  }
}

// ---------------------------------------------------------------------------
// Split fp32 -> int16 fixed-point -> i8 planes (a = hi byte, b = lo byte)
// ---------------------------------------------------------------------------
__global__ __launch_bounds__(256) void k_split_i8(const float* __restrict__ src,
                                                  signed char* __restrict__ pa,
                                                  signed char* __restrict__ pb,
                                                  float S, int n){
  const int i = blockIdx.x*256 + threadIdx.x;
  if(i < n){
    signed char a, b;
    i16split(src[i], S, a, b);
    pa[i] = a; pb[i] = b;
  }
}

// ---------------------------------------------------------------------------
// Kernel A0 (step 0 only): bf16x2 3-product MFMA LSTM step from enc_h
// (unbounded range -> bf16 hi/lo). Double-buffered; writes c + i8 h planes.
// ---------------------------------------------------------------------------
__global__ __launch_bounds__(256, 2) void k_lstm_bf16(
    const unsigned short* __restrict__ hh, const unsigned short* __restrict__ hl,
    const float* __restrict__ cin,
    signed char* __restrict__ ha, signed char* __restrict__ hb,
    float* __restrict__ cout,
    const unsigned short* __restrict__ Whh_hi, const unsigned short* __restrict__ Whh_lo,
    const float* __restrict__ bih, const float* __restrict__ bhh)
{
  __shared__ unsigned short lds[2][16384];
  const int tid = threadIdx.x;
  const int wave = tid >> 6, lane = tid & 63;
  const int mb = blockIdx.x * 128;
  const int jb = blockIdx.y * 32;
  const int b_wave = (wave & 1) * 64;
  const int j_wave = (wave >> 1) * 16;
  const int fr = lane & 15, q = lane >> 4;
  const int lr = lane >> 2, jj = lane & 3;

  auto stage = [&](int k0, int bsel){
    unsigned short* Whi = lds[bsel];
    unsigned short* Wlo = lds[bsel] + 4096;
    unsigned short* Hhi = lds[bsel] + 8192;
    unsigned short* Hlo = lds[bsel] + 12288;
#pragma unroll
    for(int p=0;p<2;p++){
      const int s = wave*2 + p;
      const int r = s*16 + lr;
      const int j = jj ^ ((r >> 1) & 3);
      const size_t ka = (size_t)k0 + j*8;
      const size_t wrow = (size_t)((r >> 5)*Hd + jb + (r & 31));
      gl_lds16(Whh_hi + wrow*Hd + ka, &Whi[s*512]);
      gl_lds16(Whh_lo + wrow*Hd + ka, &Wlo[s*512]);
      gl_lds16(hh + (size_t)(mb + r)*Hd + ka, &Hhi[s*512]);
      gl_lds16(hl + (size_t)(mb + r)*Hd + ka, &Hlo[s*512]);
    }
  };

  stage(0, 0);

  const int j0 = jb + j_wave + q*4;
  float bsum[4][4];
#pragma unroll
  for(int g=0;g<4;g++){
    float4 a = *(const float4*)&bih[g*Hd + j0];
    float4 b = *(const float4*)&bhh[g*Hd + j0];
    bsum[g][0]=a.x+b.x; bsum[g][1]=a.y+b.y; bsum[g][2]=a.z+b.z; bsum[g][3]=a.w+b.w;
  }

  f32x4 acc[4][4];
#pragma unroll
  for(int g=0;g<4;g++)
#pragma unroll
    for(int bt=0;bt<4;bt++) acc[g][bt] = (f32x4){0.f,0.f,0.f,0.f};

  for(int kc=0; kc<16; kc++){
    __syncthreads();
    if(kc < 15) stage((kc+1)*32, (kc+1)&1);

    const unsigned short* Whi = lds[kc&1];
    const unsigned short* Wlo = lds[kc&1] + 4096;
    const unsigned short* Hhi = lds[kc&1] + 8192;
    const unsigned short* Hlo = lds[kc&1] + 12288;

    short8 wh[4], wl[4], hf[4], lf[4];
#pragma unroll
    for(int g=0;g<4;g++){
      const int r = g*32 + j_wave + fr;
      const int off = r*32 + ((q ^ ((r >> 1) & 3)) << 3);
      wh[g] = *(const short8*)&Whi[off];
      wl[g] = *(const short8*)&Wlo[off];
    }
#pragma unroll
    for(int bt=0;bt<4;bt++){
      const int r = b_wave + bt*16 + fr;
      const int off = r*32 + ((q ^ ((r >> 1) & 3)) << 3);
      hf[bt] = *(const short8*)&Hhi[off];
      lf[bt] = *(const short8*)&Hlo[off];
    }
#pragma unroll
    for(int g=0;g<4;g++)
#pragma unroll
      for(int bt=0;bt<4;bt++){
        acc[g][bt] = __builtin_amdgcn_mfma_f32_16x16x32_bf16(wh[g], hf[bt], acc[g][bt], 0,0,0);
        acc[g][bt] = __builtin_amdgcn_mfma_f32_16x16x32_bf16(wh[g], lf[bt], acc[g][bt], 0,0,0);
        acc[g][bt] = __builtin_amdgcn_mfma_f32_16x16x32_bf16(wl[g], hf[bt], acc[g][bt], 0,0,0);
      }
  }

#pragma unroll
  for(int bt=0;bt<4;bt++){
    const int b = mb + b_wave + bt*16 + fr;
    const size_t idx = (size_t)b*Hd + j0;
    float gv[4][4];
#pragma unroll
    for(int g=0;g<4;g++)
#pragma unroll
      for(int r=0;r<4;r++) gv[g][r] = acc[g][bt][r] + bsum[g][r];
    float co[4];
    *(float4*)co = *(const float4*)&cin[idx];
    float cn[4];
    signed char a4[4], b4[4];
#pragma unroll
    for(int r=0;r<4;r++){
      const float I = sigm_f(gv[0][r]);
      const float F = sigm_f(gv[1][r]);
      const float G = tanh_f(gv[2][r]);
      const float O = sigm_f(gv[3][r]);
      cn[r] = F*co[r] + I*G;
      const float hn = O*tanh_f(cn[r]);
      i16split(hn, 32767.0f, a4[r], b4[r]);
    }
    *(float4*)&cout[idx] = *(float4*)cn;
    *(char4*)&ha[idx] = *(char4*)a4;
    *(char4*)&hb[idx] = *(char4*)b4;
  }
}

// ---------------------------------------------------------------------------
// Kernel A (steps >=1): int16/i8 fixed-point LSTM step.
// 3x mfma_i32_16x16x64_i8 per K=64 chunk (hihi->acc1; hilo+lohi->acc2).
// Block 128 batch x 32 j x 4 gates; dbuf 2x32KB; 8 chunks; grid 64x16.
// ---------------------------------------------------------------------------
__global__ __launch_bounds__(256, 2) void k_lstm_i8(
    const signed char* __restrict__ hA, const signed char* __restrict__ hB,
    const float* __restrict__ cin,
    signed char* __restrict__ hoA, signed char* __restrict__ hoB,
    float* __restrict__ cout,
    const signed char* __restrict__ WA, const signed char* __restrict__ WB,
    const float* __restrict__ WihT, const float* __restrict__ bih,
    const float* __restrict__ bhh, const int* __restrict__ xidx)
{
  __shared__ unsigned char lds[2][32768];   // per buf: Wa 8K | Wb 8K | Ha 8K | Hb 8K
  const int tid = threadIdx.x;
  const int wave = tid >> 6, lane = tid & 63;
  const int mb = blockIdx.x * 128;
  const int jb = blockIdx.y * 32;
  const int b_wave = (wave & 1) * 64;
  const int j_wave = (wave >> 1) * 16;
  const int fr = lane & 15, q = lane >> 4;
  const int lr = lane >> 2, jj = lane & 3;

  auto stage = [&](int k0, int bsel){
    unsigned char* Wa = lds[bsel];
    unsigned char* Wb = lds[bsel] + 8192;
    unsigned char* Ha = lds[bsel] + 16384;
    unsigned char* Hb = lds[bsel] + 24576;
#pragma unroll
    for(int p=0;p<2;p++){
      const int s = wave*2 + p;
      const int r = s*16 + lr;                 // tile row 0..127
      const int j = jj ^ ((r >> 1) & 3);       // swizzled 16B slot
      const size_t ka = (size_t)k0 + j*16;
      const size_t wrow = (size_t)((r >> 5)*Hd + jb + (r & 31));
      gl_lds16(WA + wrow*Hd + ka, &Wa[s*1024]);
      gl_lds16(WB + wrow*Hd + ka, &Wb[s*1024]);
      gl_lds16(hA + (size_t)(mb + r)*Hd + ka, &Ha[s*1024]);
      gl_lds16(hB + (size_t)(mb + r)*Hd + ka, &Hb[s*1024]);
    }
  };

  stage(0, 0);

  // xidx prefetch (latency-hidden behind GEMM)
  int xid[4];
#pragma unroll
  for(int bt=0;bt<4;bt++)
    xid[bt] = xidx[mb + b_wave + bt*16 + fr];

  int4v acc1[4][4], acc2[4][4];               // [gate][bt]
#pragma unroll
  for(int g=0;g<4;g++)
#pragma unroll
    for(int bt=0;bt<4;bt++){
      acc1[g][bt] = (int4v){0,0,0,0};
      acc2[g][bt] = (int4v){0,0,0,0};
    }

  for(int kc=0; kc<8; kc++){
    __syncthreads();
    if(kc < 7) stage((kc+1)*64, (kc+1)&1);

    const unsigned char* Wa = lds[kc&1];
    const unsigned char* Wb = lds[kc&1] + 8192;
    const unsigned char* Ha = lds[kc&1] + 16384;
    const unsigned char* Hb = lds[kc&1] + 24576;

    int4v wa[4], wb[4], hf[4], lf[4];
#pragma unroll
    for(int g=0;g<4;g++){
      const int r = g*32 + j_wave + fr;
      const int off = r*64 + ((q ^ ((r >> 1) & 3)) << 4);
      wa[g] = *(const int4v*)&Wa[off];
      wb[g] = *(const int4v*)&Wb[off];
    }
#pragma unroll
    for(int bt=0;bt<4;bt++){
      const int r = b_wave + bt*16 + fr;
      const int off = r*64 + ((q ^ ((r >> 1) & 3)) << 4);
      hf[bt] = *(const int4v*)&Ha[off];
      lf[bt] = *(const int4v*)&Hb[off];
    }
#pragma unroll
    for(int g=0;g<4;g++)
#pragma unroll
      for(int bt=0;bt<4;bt++){
        acc1[g][bt] = __builtin_amdgcn_mfma_i32_16x16x64_i8(wa[g], hf[bt], acc1[g][bt], 0,0,0);
        acc2[g][bt] = __builtin_amdgcn_mfma_i32_16x16x64_i8(wa[g], lf[bt], acc2[g][bt], 0,0,0);
        acc2[g][bt] = __builtin_amdgcn_mfma_i32_16x16x64_i8(wb[g], hf[bt], acc2[g][bt], 0,0,0);
      }
  }

  // ---- epilogue (bias loads here to keep main-loop VGPR pressure down)
  const int j0 = jb + j_wave + q*4;
  float bsum[4][4];
#pragma unroll
  for(int g=0;g<4;g++){
    float4 a = *(const float4*)&bih[g*Hd + j0];
    float4 b = *(const float4*)&bhh[g*Hd + j0];
    bsum[g][0]=a.x+b.x; bsum[g][1]=a.y+b.y; bsum[g][2]=a.z+b.z; bsum[g][3]=a.w+b.w;
  }
#pragma unroll
  for(int bt=0;bt<4;bt++){
    const int b = mb + b_wave + bt*16 + fr;
    const size_t idx = (size_t)b*Hd + j0;
    float gv[4][4];
#pragma unroll
    for(int g=0;g<4;g++)
#pragma unroll
      for(int r=0;r<4;r++)
        gv[g][r] = fmaf(C1I, (float)acc1[g][bt][r],
                   fmaf(C2I, (float)acc2[g][bt][r], bsum[g][r]));
    {
      const float* grow = WihT + (size_t)xid[bt]*G4 + j0;
#pragma unroll
      for(int g=0;g<4;g++){
        float4 x = *(const float4*)&grow[g*Hd];
        gv[g][0]+=x.x; gv[g][1]+=x.y; gv[g][2]+=x.z; gv[g][3]+=x.w;
      }
    }
    float co[4];
    *(float4*)co = *(const float4*)&cin[idx];
    float cn[4];
    signed char a4[4], b4[4];
#pragma unroll
    for(int r=0;r<4;r++){
      const float I = sigm_f(gv[0][r]);
      const float F = sigm_f(gv[1][r]);
      const float G = tanh_f(gv[2][r]);
      const float O = sigm_f(gv[3][r]);
      cn[r] = F*co[r] + I*G;
      const float hn = O*tanh_f(cn[r]);
      i16split(hn, 32767.0f, a4[r], b4[r]);
    }
    *(float4*)&cout[idx] = *(float4*)cn;
    *(char4*)&hoA[idx] = *(char4*)a4;
    *(char4*)&hoB[idx] = *(char4*)b4;
  }
}

// ---------------------------------------------------------------------------
// Kernel B: logits stats via i8 fixed-point (same 3-MFMA scheme).
// 128x128 tile, dbuf; per-row (max, argmax, sumexp) per 64-col slab.
// ---------------------------------------------------------------------------
__global__ __launch_bounds__(256, 2) void k_logits_i8(
    const signed char* __restrict__ hA, const signed char* __restrict__ hB,
    const signed char* __restrict__ WoA, const signed char* __restrict__ WoB,
    const float* __restrict__ bout,
    float* __restrict__ statM, float* __restrict__ statS, int* __restrict__ statI)
{
  __shared__ unsigned char lds[2][32768];   // Ha | Hb | Wa | Wb (8K each)
  const int tid = threadIdx.x;
  const int wave = tid >> 6, lane = tid & 63;
  const int mb = blockIdx.x * 128;
  const int vb = blockIdx.y * 128;
  const int m_wave = (wave & 1) * 64;
  const int n_wave = (wave >> 1) * 64;
  const int fr = lane & 15, q = lane >> 4;
  const int lr = lane >> 2, jj = lane & 3;

  auto stage = [&](int k0, int bsel){
    unsigned char* Ha = lds[bsel];
    unsigned char* Hb = lds[bsel] + 8192;
    unsigned char* Wa = lds[bsel] + 16384;
    unsigned char* Wb = lds[bsel] + 24576;
#pragma unroll
    for(int p=0;p<2;p++){
      const int s = wave*2 + p;
      const int r = s*16 + lr;
      const int j = jj ^ ((r >> 1) & 3);
      const size_t ka = (size_t)k0 + j*16;
      gl_lds16(hA + (size_t)(mb + r)*Hd + ka, &Ha[s*1024]);
      gl_lds16(hB + (size_t)(mb + r)*Hd + ka, &Hb[s*1024]);
      gl_lds16(WoA + (size_t)(vb + r)*Hd + ka, &Wa[s*1024]);
      gl_lds16(WoB + (size_t)(vb + r)*Hd + ka, &Wb[s*1024]);
    }
  };

  stage(0, 0);

  int4v acc1[4][4], acc2[4][4];              // [nt][mt]
#pragma unroll
  for(int nt=0;nt<4;nt++)
#pragma unroll
    for(int mt=0;mt<4;mt++){
      acc1[nt][mt] = (int4v){0,0,0,0};
      acc2[nt][mt] = (int4v){0,0,0,0};
    }

  for(int kc=0; kc<8; kc++){
    __syncthreads();
    if(kc < 7) stage((kc+1)*64, (kc+1)&1);

    const unsigned char* Ha = lds[kc&1];
    const unsigned char* Hb = lds[kc&1] + 8192;
    const unsigned char* Wa = lds[kc&1] + 16384;
    const unsigned char* Wb = lds[kc&1] + 24576;

    int4v ah[4], al[4], bh[4], bl[4];
#pragma unroll
    for(int mt=0;mt<4;mt++){
      const int r = m_wave + mt*16 + fr;
      const int off = r*64 + ((q ^ ((r >> 1) & 3)) << 4);
      ah[mt] = *(const int4v*)&Ha[off];
      al[mt] = *(const int4v*)&Hb[off];
    }
#pragma unroll
    for(int nt=0;nt<4;nt++){
      const int r = n_wave + nt*16 + fr;
      const int off = r*64 + ((q ^ ((r >> 1) & 3)) << 4);
      bh[nt] = *(const int4v*)&Wa[off];
      bl[nt] = *(const int4v*)&Wb[off];
    }
#pragma unroll
    for(int nt=0;nt<4;nt++)
#pragma unroll
      for(int mt=0;mt<4;mt++){
        acc1[nt][mt] = __builtin_amdgcn_mfma_i32_16x16x64_i8(ah[mt], bh[nt], acc1[nt][mt], 0,0,0);
        acc2[nt][mt] = __builtin_amdgcn_mfma_i32_16x16x64_i8(ah[mt], bl[nt], acc2[nt][mt], 0,0,0);
        acc2[nt][mt] = __builtin_amdgcn_mfma_i32_16x16x64_i8(al[mt], bh[nt], acc2[nt][mt], 0,0,0);
      }
  }

  const int slab = blockIdx.y*2 + (wave >> 1);
  float bo[4];
  int vv[4];
#pragma unroll
  for(int nt=0;nt<4;nt++){
    vv[nt] = vb + n_wave + nt*16 + fr;
    bo[nt] = bout[vv[nt]];
  }
#pragma unroll
  for(int mt=0;mt<4;mt++){
#pragma unroll
    for(int reg=0;reg<4;reg++){
      float lg[4];
#pragma unroll
      for(int nt=0;nt<4;nt++)
        lg[nt] = fmaf(C1I, (float)acc1[nt][mt][reg],
                 fmaf(C2I, (float)acc2[nt][mt][reg], bo[nt]));
      float vmax = lg[0];
      int   imax = vv[0];
#pragma unroll
      for(int nt=1;nt<4;nt++){
        if(lg[nt] > vmax || (lg[nt] == vmax && vv[nt] < imax)){ vmax = lg[nt]; imax = vv[nt]; }
      }
#pragma unroll
      for(int off=1; off<16; off<<=1){
        const float vo = __shfl_xor(vmax, off);
        const int   io = __shfl_xor(imax, off);
        if(vo > vmax || (vo == vmax && io < imax)){ vmax = vo; imax = io; }
      }
      float s = 0.0f;
#pragma unroll
      for(int nt=0;nt<4;nt++) s += __expf(lg[nt] - vmax);
#pragma unroll
      for(int off=1; off<16; off<<=1) s += __shfl_xor(s, off);
      if(fr == 0){
        const int m = mb + m_wave + mt*16 + q*4 + reg;
        statM[(size_t)slab*Bsz + m] = vmax;
        statS[(size_t)slab*Bsz + m] = s;
        statI[(size_t)slab*Bsz + m] = imax;
      }
    }
  }
}

// ---------------------------------------------------------------------------
// Kernel C: merge 8 slabs per row; write masks/lp/xidx + one-hot message.
// ---------------------------------------------------------------------------
__global__ __launch_bounds__(256) void k_merge(
    const float* __restrict__ statM, const float* __restrict__ statS,
    const int* __restrict__ statI,
    float* __restrict__ msg, float* __restrict__ masks_out,
    float* __restrict__ lp_out, float* __restrict__ lpbuf,
    float* __restrict__ mbuf, int* __restrict__ xidx, int step)
{
  __shared__ int gI[32];
  const int tid = threadIdx.x;
  const int mb = blockIdx.x * 32;

  if(tid < 32){
    const int row = mb + tid;
    float gm = statM[row]; int gi = statI[row];
#pragma unroll
    for(int s=1;s<8;s++){
      const float m = statM[(size_t)s*Bsz + row];
      if(m > gm){ gm = m; gi = statI[(size_t)s*Bsz + row]; }
    }
    float tot = 0.0f;
#pragma unroll
    for(int s=0;s<8;s++)
      tot += statS[(size_t)s*Bsz + row] * __expf(statM[(size_t)s*Bsz + row] - gm);
    const float logp = -__logf(tot);
    const float mo  = (step == 0) ? 1.0f : mbuf[row];
    const float lpo = (step == 0) ? 0.0f : lpbuf[row];
    const float lpn = lpo + logp * mo;
    masks_out[(size_t)step * Bsz + row] = mo;
    lp_out[row] = lpn;
    lpbuf[row]  = lpn;
    mbuf[row]   = mo * ((gi == Vd-1) ? 0.0f : 1.0f);
    xidx[row]   = gi;
    gI[tid] = gi;
  }
  __syncthreads();

  const int r  = tid >> 3;
  const int c8 = tid & 7;
  const int gi = gI[r];
  float* mrow = msg + ((size_t)step * Bsz + mb + r) * Vd;
#pragma unroll
  for(int i=0;i<16;i++){
    const int c = (i*8 + c8) * 4;
    float4 v;
    v.x = (c   == gi) ? 1.0f : 0.0f;
    v.y = (c+1 == gi) ? 1.0f : 0.0f;
    v.z = (c+2 == gi) ? 1.0f : 0.0f;
    v.w = (c+3 == gi) ? 1.0f : 0.0f;
    *(float4*)&mrow[c] = v;
  }
}

// ---------------------------------------------------------------------------
extern "C" void kernel_launch(void* const* d_in, const int* in_sizes, int n_in,
                              void* d_out, int out_size, void* d_ws, size_t ws_size,
                              hipStream_t stream) {
  const float* enc_h = (const float*)d_in[0];
  const float* enc_c = (const float*)d_in[1];
  const float* Wih   = (const float*)d_in[2];
  const float* Whh   = (const float*)d_in[3];
  const float* bih   = (const float*)d_in[4];
  const float* bhh   = (const float*)d_in[5];
  const float* Wout  = (const float*)d_in[6];
  const float* bout  = (const float*)d_in[7];

  float* out_msg   = (float*)d_out;                       // [16][8192][512]
  float* out_masks = out_msg + (size_t)Ld * Bsz * Vd;     // [16][1][8192]
  float* out_lp    = out_masks + (size_t)Ld * Bsz;        // [8192]

  char* ws = (char*)d_ws;
  float* WihT  = (float*)ws;          ws += (size_t)Vd * G4 * 4;           // 4 MB
  unsigned short* WhhHi = (unsigned short*)ws; ws += (size_t)G4 * Hd * 2;  // 2 MB
  unsigned short* WhhLo = (unsigned short*)ws; ws += (size_t)G4 * Hd * 2;  // 2 MB
  unsigned short* encHi = (unsigned short*)ws; ws += (size_t)Bsz * Hd * 2; // 8 MB
  unsigned short* encLo = (unsigned short*)ws; ws += (size_t)Bsz * Hd * 2; // 8 MB
  signed char* WhhA = (signed char*)ws; ws += (size_t)G4 * Hd;             // 1 MB
  signed char* WhhB = (signed char*)ws; ws += (size_t)G4 * Hd;             // 1 MB
  signed char* WoA  = (signed char*)ws; ws += (size_t)Vd * Hd;             // 256 KB
  signed char* WoB  = (signed char*)ws; ws += (size_t)Vd * Hd;             // 256 KB
  signed char* ha0  = (signed char*)ws; ws += (size_t)Bsz * Hd;            // 4 MB
  signed char* hb0  = (signed char*)ws; ws += (size_t)Bsz * Hd;
  signed char* ha1  = (signed char*)ws; ws += (size_t)Bsz * Hd;
  signed char* hb1  = (signed char*)ws; ws += (size_t)Bsz * Hd;
  float* cbuf   = (float*)ws;  ws += (size_t)Bsz * Hd * 4;                 // 16 MB
  float* statM  = (float*)ws;  ws += (size_t)8 * Bsz * 4;
  float* statS  = (float*)ws;  ws += (size_t)8 * Bsz * 4;
  int*   statI  = (int*)ws;    ws += (size_t)8 * Bsz * 4;
  float* lpbuf  = (float*)ws;  ws += (size_t)Bsz * 4;
  float* mbuf   = (float*)ws;  ws += (size_t)Bsz * 4;
  int*   xidx   = (int*)ws;    ws += (size_t)Bsz * 4;

  k_transpose<<<dim3(Vd/32, G4/32), dim3(32,8), 0, stream>>>(Wih, WihT);
  k_split<<<(G4*Hd+255)/256, 256, 0, stream>>>(Whh, WhhHi, WhhLo, G4*Hd);
  k_split<<<(Bsz*Hd+255)/256, 256, 0, stream>>>(enc_h, encHi, encLo, Bsz*Hd);
  k_split_i8<<<(G4*Hd+255)/256, 256, 0, stream>>>(Whh, WhhA, WhhB, 524288.0f, G4*Hd);
  k_split_i8<<<(Vd*Hd+255)/256, 256, 0, stream>>>(Wout, WoA, WoB, 524288.0f, Vd*Hd);

  for(int t=0; t<Ld; t++){
    signed char* haOut = (t & 1) ? ha1 : ha0;
    signed char* hbOut = (t & 1) ? hb1 : hb0;
    const signed char* haIn = (t & 1) ? ha0 : ha1;
    const signed char* hbIn = (t & 1) ? hb0 : hb1;

    if(t == 0){
      k_lstm_bf16<<<dim3(Bsz/128, Hd/32), 256, 0, stream>>>(
          encHi, encLo, enc_c, haOut, hbOut, cbuf, WhhHi, WhhLo, bih, bhh);
    } else {
      k_lstm_i8<<<dim3(Bsz/128, Hd/32), 256, 0, stream>>>(
          haIn, hbIn, cbuf, haOut, hbOut, cbuf, WhhA, WhhB, WihT, bih, bhh, xidx);
    }
    k_logits_i8<<<dim3(Bsz/128, Vd/128), 256, 0, stream>>>(
        haOut, hbOut, WoA, WoB, bout, statM, statS, statI);
    k_merge<<<Bsz/32, 256, 0, stream>>>(statM, statS, statI,
                                        out_msg, out_masks, out_lp,
                                        lpbuf, mbuf, xidx, t);
  }
}